// Round 7
// baseline (2291.682 us; speedup 1.0000x reference)
//
#include <hip/hip_runtime.h>

#define B 4096
#define J 16
#define HID 128
#define INTER 64
#define NLAYERS 4
#define NEGV -9000000000000000.0f
#define ELEMS ((size_t)B*16*128)
#define NREP 16
#define SLOT 4096

typedef __attribute__((ext_vector_type(8))) short short8;
typedef __attribute__((ext_vector_type(4))) float f32x4;

static __device__ __forceinline__ unsigned short f2bf(float x) {
    unsigned u = __float_as_uint(x);
    unsigned r = u + 0x7fffu + ((u >> 16) & 1u);
    return (unsigned short)(r >> 16);
}
static __device__ __forceinline__ void splitbf(float x, unsigned short& h, unsigned short& l) {
    h = f2bf(x);
    float hf = __uint_as_float((unsigned)h << 16);
    l = f2bf(x - hf);
}
static __device__ __forceinline__ void splitbf4(float4 v, uint2& hh, uint2& ll) {
    unsigned short h0,l0,h1,l1,h2,l2,h3,l3;
    splitbf(v.x,h0,l0); splitbf(v.y,h1,l1); splitbf(v.z,h2,l2); splitbf(v.w,h3,l3);
    hh = make_uint2((unsigned)h0 | ((unsigned)h1<<16), (unsigned)h2 | ((unsigned)h3<<16));
    ll = make_uint2((unsigned)l0 | ((unsigned)l1<<16), (unsigned)l2 | ((unsigned)l3<<16));
}
static __device__ __forceinline__ f32x4 mfma16(short8 a, short8 b, f32x4 c) {
    return __builtin_amdgcn_mfma_f32_16x16x32_bf16(a, b, c, 0, 0, 0);
}
static __device__ __forceinline__ f32x4 mfma_split(short8 ah, short8 al,
                                                   short8 bh, short8 bl, f32x4 acc) {
    acc = mfma16(ah, bh, acc);
    acc = mfma16(ah, bl, acc);
    acc = mfma16(al, bh, acc);
    return acc;
}
static __device__ __forceinline__ float bfpair(unsigned short h, unsigned short l) {
    return __uint_as_float((unsigned)h << 16) + __uint_as_float((unsigned)l << 16);
}

// ---------------------------------------------------------------- fused prep
#define WB_N   262144
#define NLW_N  122880
#define NLWW_N 40960
#define PREPW_BLKS 1664   // (WB_N+NLW_N+NLWW_N)/256 exactly
__global__ __launch_bounds__(256) void prep_all_kernel(
        const float* __restrict__ W_res,
        const float* __restrict__ g_w, const float* __restrict__ t_w,
        const float* __restrict__ p_w, const float* __restrict__ W_w,
        unsigned short* __restrict__ Wbh, unsigned short* __restrict__ Wbl,
        unsigned short* __restrict__ nlwh, unsigned short* __restrict__ nlwl,
        unsigned short* __restrict__ nlWh, unsigned short* __restrict__ nlWl,
        const float* __restrict__ e_in, const float* __restrict__ e_res,
        const float* __restrict__ e_out,
        const int* __restrict__ rows, const int* __restrict__ cols, int nnz,
        float* __restrict__ off_all, float* __restrict__ diag_all,
        const float* __restrict__ t_b, const float* __restrict__ cp_w,
        float* __restrict__ vt, float* __restrict__ ct,
        float* __restrict__ stats) {
    int blk = blockIdx.x, t = threadIdx.x;
    if (blk < PREPW_BLKS) {
        int i = blk * 256 + t;
        unsigned short h, l;
        if (i < WB_N) {
            int lay = i >> 15, rem = i & 32767, n = rem >> 8, k = rem & 255;
            int d = k >> 7, f = k & 127;
            splitbf(W_res[(((lay << 1) | d) * 128 + f) * 128 + n], h, l);
            Wbh[i] = h; Wbl[i] = l;
        } else if (i < WB_N + NLW_N) {
            int j = i - WB_N;
            int lay = j / 24576, r2 = j % 24576;
            int conv = r2 >> 13, oc = r2 & 8191;
            const float* src = conv == 0 ? g_w : conv == 1 ? t_w : p_w;
            splitbf(src[lay * 8192 + oc], h, l);
            nlwh[j] = h; nlwl[j] = l;
        } else {
            int j = i - WB_N - NLW_N;
            splitbf(W_w[j], h, l);
            nlWh[j] = h; nlWl[j] = l;
        }
    } else if (blk < PREPW_BLKS + 10) {
        if (t < 16) {
            int m = blk - PREPW_BLKS;
            int i = t;
            const float* e = (m == 0) ? e_in : (m <= 8) ? e_res + (size_t)(m - 1) * nnz : e_out;
            float l[16];
            for (int j = 0; j < 16; j++) l[j] = NEGV;
            for (int k = 0; k < nnz; k++)
                if (rows[k] == i) l[cols[k]] = e[k];
            float mx = l[0];
            for (int j = 1; j < 16; j++) mx = fmaxf(mx, l[j]);
            float ex[16], s = 0.f;
            for (int j = 0; j < 16; j++) { ex[j] = expf(l[j] - mx); s += ex[j]; }
            float inv = 1.f / s;
            for (int j = 0; j < 16; j++) {
                float a = ex[j] * inv;
                if (j == i) { diag_all[m * 16 + i] = a; a = 0.f; }
                off_all[m * 256 + i * 16 + j] = a;
            }
        }
    } else if (blk < PREPW_BLKS + 15) {
        if (t < 128) {
            int l = blk - PREPW_BLKS - 10, c = t;
            float s = 0.f;
            for (int c2 = 0; c2 < 64; c2++)
                s += cp_w[l * 128 + c2] * t_w[(l * 64 + c2) * 128 + c];
            vt[l * 128 + c] = s;
            if (c == 0) {
                float s2 = 0.f;
                for (int c2 = 0; c2 < 64; c2++) s2 += cp_w[l * 128 + c2] * t_b[l * 64 + c2];
                ct[l] = s2;
            }
        }
    } else {
        int sl_ = blk - PREPW_BLKS - 15;   // 0..13
        float* dst = stats + (size_t)sl_ * SLOT;
        #pragma unroll
        for (int u = 0; u < 16; u++) dst[t + u * 256] = 0.f;
    }
}

// ---------------------------------------------------------------- gconv in (F=2)
__global__ __launch_bounds__(256) void gconv_in_kernel(
        const float* __restrict__ x, const float* __restrict__ W,
        const float* __restrict__ bias, const float* __restrict__ off,
        const float* __restrict__ diag, float* __restrict__ out,
        float* __restrict__ stats_out) {
    __shared__ float xs[16][2];
    __shared__ float gs[16][2];
    __shared__ float red[512];
    int b = blockIdx.x, t = threadIdx.x;
    if (t < 32) xs[t >> 1][t & 1] = x[b * 32 + t];
    __syncthreads();
    if (t < 32) {
        int i = t >> 1, f = t & 1;
        float g = 0.f;
        #pragma unroll
        for (int j = 0; j < 16; j++) g += off[i * 16 + j] * xs[j][f];
        gs[i][f] = g;
    }
    __syncthreads();
    int o = t & 127;
    float w00 = W[o], w01 = W[128 + o], w10 = W[256 + o], w11 = W[384 + o], bo = bias[o];
    float s = 0.f, q = 0.f;
    float vals[8];
    #pragma unroll
    for (int u = 0; u < 8; u++) {
        int idx = t + u * 256;
        int i = idx >> 7;
        float v = diag[i] * (xs[i][0] * w00 + xs[i][1] * w01)
                + gs[i][0] * w10 + gs[i][1] * w11 + bo;
        vals[u] = v;
        s += v; q += v * v;
    }
    red[t] = s; red[256 + t] = q;
    __syncthreads();
    float* so = stats_out + (b & (NREP - 1)) * 256;
    if (t < 128) {
        atomicAdd(&so[t], red[t] + red[t + 128]);
        atomicAdd(&so[128 + t], red[256 + t] + red[256 + t + 128]);
    }
    #pragma unroll
    for (int u = 0; u < 8; u++)
        out[(size_t)b * 2048 + t + u * 256] = vals[u];
}

// ---------------------------------------------------------------- gconv 128->128
// 2 samples per block; stats finalize fused. Store-motion: zdst float4s and
// sample-0 stats atomics deferred past the last barrier (no vmcnt(0) drain
// of global stores at any mid-kernel barrier).
__global__ __launch_bounds__(256, 6) void gconv_mfma_kernel(
        const float* src, const float* wy,
        const float* __restrict__ stats_in,
        const float* __restrict__ bn_g, const float* __restrict__ bn_b,
        const int* __restrict__ restored, float* zdst,
        const unsigned short* __restrict__ Wbh,
        const unsigned short* __restrict__ Wbl,
        const float* __restrict__ bias,
        const float* __restrict__ off, const float* __restrict__ diag,
        float* dst, float* __restrict__ stats_out) {
    __shared__ float hraw[16][132];
    __shared__ __align__(16) unsigned short ksh[16][264];
    __shared__ __align__(16) unsigned short ksl[16][264];
    __shared__ float offs[256];
    __shared__ float diags[16];
    int t = threadIdx.x;
    offs[t] = off[t];
    if (t < 16) diags[t] = diag[t];
    float* hrawf = &hraw[0][0];
    {
        float ssum = 0.f;
        #pragma unroll
        for (int rr = 0; rr < NREP; rr++) ssum += stats_in[rr * 256 + t];
        hrawf[t] = ssum;
    }
    int c4 = (4 * t) & 127;
    int r0 = t >> 5;
    int ro0 = 0, ro1 = 0;
    if (wy) { ro0 = restored[r0]; ro1 = restored[r0 + 8]; }
    int b0 = blockIdx.x;
    const float4* src4 = (const float4*)src;
    const float4* wy4  = (const float4*)wy;
    float4 sv0 = src4[(size_t)b0 * 512 + t];
    float4 sv1 = src4[(size_t)b0 * 512 + 256 + t];
    float4 wv0 = make_float4(0,0,0,0), wv1 = make_float4(0,0,0,0);
    if (wy) {
        wv0 = wy4[(size_t)b0 * 512 + ro0 * 32 + (c4 >> 2)];
        wv1 = wy4[(size_t)b0 * 512 + ro1 * 32 + (c4 >> 2)];
    }
    __syncthreads();
    float4 m4, sc4, bb4;
    {
        const float K = 1.f / 65536.f;
        float4 g4 = *(const float4*)&bn_g[c4];
        bb4 = *(const float4*)&bn_b[c4];
        float m0 = hrawf[c4]     * K, m1 = hrawf[c4 + 1] * K;
        float m2 = hrawf[c4 + 2] * K, m3 = hrawf[c4 + 3] * K;
        float i0 = rsqrtf(hrawf[c4 + 128]     * K - m0 * m0 + 1e-5f);
        float i1 = rsqrtf(hrawf[c4 + 129] * K - m1 * m1 + 1e-5f);
        float i2 = rsqrtf(hrawf[c4 + 130] * K - m2 * m2 + 1e-5f);
        float i3 = rsqrtf(hrawf[c4 + 131] * K - m3 * m3 + 1e-5f);
        m4 = make_float4(m0, m1, m2, m3);
        sc4 = make_float4(i0 * g4.x, i1 * g4.y, i2 * g4.z, i3 * g4.w);
    }
    __syncthreads();
    int wv_ = t >> 6, lane = t & 63;
    int mn = lane & 15, kq = (lane >> 4) << 3, qr = (lane >> 4) << 2;
    float4 zs0a, zs0b, zs1a, zs1b;          // deferred zdst values
    float ds0 = 0.f, dq0 = 0.f, ds1 = 0.f, dq1 = 0.f;  // deferred s=0 stats

    for (int s = 0; s < 2; s++) {
        int bb_ = blockIdx.x + s * 2048;
        {
            float4 v = sv0;
            if (wy) {
                v.x += (wv0.x - m4.x) * sc4.x + bb4.x;
                v.y += (wv0.y - m4.y) * sc4.y + bb4.y;
                v.z += (wv0.z - m4.z) * sc4.z + bb4.z;
                v.w += (wv0.w - m4.w) * sc4.w + bb4.w;
                if (s == 0) zs0a = v; else zs1a = v;
            } else {
                v.x = fmaxf((v.x - m4.x) * sc4.x + bb4.x, 0.f);
                v.y = fmaxf((v.y - m4.y) * sc4.y + bb4.y, 0.f);
                v.z = fmaxf((v.z - m4.z) * sc4.z + bb4.z, 0.f);
                v.w = fmaxf((v.w - m4.w) * sc4.w + bb4.w, 0.f);
            }
            *(float4*)&hraw[r0][c4] = v;
            v = sv1;
            if (wy) {
                v.x += (wv1.x - m4.x) * sc4.x + bb4.x;
                v.y += (wv1.y - m4.y) * sc4.y + bb4.y;
                v.z += (wv1.z - m4.z) * sc4.z + bb4.z;
                v.w += (wv1.w - m4.w) * sc4.w + bb4.w;
                if (s == 0) zs0b = v; else zs1b = v;
            } else {
                v.x = fmaxf((v.x - m4.x) * sc4.x + bb4.x, 0.f);
                v.y = fmaxf((v.y - m4.y) * sc4.y + bb4.y, 0.f);
                v.z = fmaxf((v.z - m4.z) * sc4.z + bb4.z, 0.f);
                v.w = fmaxf((v.w - m4.w) * sc4.w + bb4.w, 0.f);
            }
            *(float4*)&hraw[r0 + 8][c4] = v;
        }
        if (s == 0) {
            int b1 = blockIdx.x + 2048;
            sv0 = src4[(size_t)b1 * 512 + t];
            sv1 = src4[(size_t)b1 * 512 + 256 + t];
            if (wy) {
                wv0 = wy4[(size_t)b1 * 512 + ro0 * 32 + (c4 >> 2)];
                wv1 = wy4[(size_t)b1 * 512 + ro1 * 32 + (c4 >> 2)];
            }
        }
        __syncthreads();
        for (int u = t; u < 512; u += 256) {
            int i = u >> 5, f4 = (u & 31) << 2;
            float4 hv = *(const float4*)&hraw[i][f4];
            float4 g = make_float4(0.f, 0.f, 0.f, 0.f);
            #pragma unroll
            for (int j = 0; j < 16; j++) {
                float w = offs[i * 16 + j];
                float4 hj = *(const float4*)&hraw[j][f4];
                g.x += w * hj.x; g.y += w * hj.y; g.z += w * hj.z; g.w += w * hj.w;
            }
            float d = diags[i];
            uint2 hh, ll;
            splitbf4(make_float4(d * hv.x, d * hv.y, d * hv.z, d * hv.w), hh, ll);
            *(uint2*)&ksh[i][f4] = hh;
            *(uint2*)&ksl[i][f4] = ll;
            splitbf4(g, hh, ll);
            *(uint2*)&ksh[i][128 + f4] = hh;
            *(uint2*)&ksl[i][128 + f4] = ll;
        }
        __syncthreads();
        int n0 = wv_ << 5;
        f32x4 acc0 = {0.f, 0.f, 0.f, 0.f}, acc1 = {0.f, 0.f, 0.f, 0.f};
        const unsigned short* wh0 = Wbh + (size_t)(n0 + mn) * 256 + kq;
        const unsigned short* wl0 = Wbl + (size_t)(n0 + mn) * 256 + kq;
        #pragma unroll
        for (int k = 0; k < 8; k++) {
            int k0 = k << 5;
            short8 ah = *(const short8*)&ksh[mn][k0 + kq];
            short8 al = *(const short8*)&ksl[mn][k0 + kq];
            acc0 = mfma_split(ah, al, *(const short8*)(wh0 + k0), *(const short8*)(wl0 + k0), acc0);
            acc1 = mfma_split(ah, al, *(const short8*)(wh0 + 4096 + k0), *(const short8*)(wl0 + 4096 + k0), acc1);
        }
        float bias0 = bias[n0 + mn], bias1 = bias[n0 + 16 + mn];
        float s0 = 0.f, q0 = 0.f, s1 = 0.f, q1 = 0.f;
        #pragma unroll
        for (int r = 0; r < 4; r++) {
            int row = qr + r;
            float v0 = acc0[r] + bias0;
            float v1 = acc1[r] + bias1;
            dst[(size_t)bb_ * 2048 + row * 128 + n0 + mn] = v0;
            dst[(size_t)bb_ * 2048 + row * 128 + n0 + 16 + mn] = v1;
            s0 += v0; q0 += v0 * v0; s1 += v1; q1 += v1 * v1;
        }
        s0 += __shfl_xor(s0, 16); s0 += __shfl_xor(s0, 32);
        q0 += __shfl_xor(q0, 16); q0 += __shfl_xor(q0, 32);
        s1 += __shfl_xor(s1, 16); s1 += __shfl_xor(s1, 32);
        q1 += __shfl_xor(q1, 16); q1 += __shfl_xor(q1, 32);
        if (s == 0) {
            ds0 = s0; dq0 = q0; ds1 = s1; dq1 = q1;
            __syncthreads();
        } else {
            float* so = stats_out + (bb_ & (NREP - 1)) * 256;
            if (lane < 16) {
                atomicAdd(&so[n0 + mn], s0);
                atomicAdd(&so[128 + n0 + mn], q0);
                atomicAdd(&so[n0 + 16 + mn], s1);
                atomicAdd(&so[128 + n0 + 16 + mn], q1);
            }
        }
    }
    // deferred: zdst stores (both samples) + sample-0 stats atomics
    if (wy) {
        ((float4*)zdst)[(size_t)b0 * 512 + t] = zs0a;
        ((float4*)zdst)[(size_t)b0 * 512 + 256 + t] = zs0b;
        ((float4*)zdst)[(size_t)(b0 + 2048) * 512 + t] = zs1a;
        ((float4*)zdst)[(size_t)(b0 + 2048) * 512 + 256 + t] = zs1b;
    }
    {
        int n0 = wv_ << 5;
        float* so = stats_out + (b0 & (NREP - 1)) * 256;
        if (lane < 16) {
            atomicAdd(&so[n0 + mn], ds0);
            atomicAdd(&so[128 + n0 + mn], dq0);
            atomicAdd(&so[n0 + 16 + mn], ds1);
            atomicAdd(&so[128 + n0 + 16 + mn], dq1);
        }
    }
}

// ---------------------------------------------------------------- nonlocal A
// 512 threads, ONE sample (grid 4096). Store-motion round: single prologue
// barrier (t<128 computes BN params straight from stats columns), h value
// held in 4 VGPRs and stored at kernel end, phase-6 wydst stores moved past
// the stats barrier (re-read WYL from LDS). No global store precedes any
// mid-kernel barrier -> no vmcnt(0) store drains. 7 barriers (was 8).
#define CG(conv, o, j) cgbuf[((conv) * 64 + (o)) * 17 + (j)]
#define WYL(o, j)      cgbuf[(o) * 17 + (j)]
__global__ __launch_bounds__(512, 8) void nl_a_kernel(
        const float* tsrc, const float* __restrict__ stats_in,
        const float* __restrict__ bn_g, const float* __restrict__ bn_b,
        const float* res,
        const unsigned short* __restrict__ nlwh,
        const unsigned short* __restrict__ nlwl,
        const float* __restrict__ g_b, const float* __restrict__ p_b,
        const float* __restrict__ cpw,
        const float* __restrict__ vt, const float* __restrict__ ctp,
        const unsigned short* __restrict__ nlWh,
        const unsigned short* __restrict__ nlWl,
        const float* __restrict__ W_b,
        const int* __restrict__ restored,
        float* hdst, float* wydst, float* __restrict__ wst) {
    __shared__ __align__(16) unsigned short xch[16][136];
    __shared__ __align__(16) unsigned short xcl[16][136];
    __shared__ float cgbuf[2176];
    __shared__ float gx[64][9];
    __shared__ float tv[16], pv[8];
    __shared__ float vtl[128];
    __shared__ __align__(16) float bnm[128], bnsc[128], bnbb[128];
    __shared__ __align__(16) unsigned short ybh[16][72];
    __shared__ __align__(16) unsigned short ybl[16][72];
    __shared__ float redS[512], redQ[512];
    int t = threadIdx.x, b = blockIdx.x;
    const float4* tsrc4 = (const float4*)tsrc;
    // issue tensor loads early; they resolve while stats reduce
    float4 sv = tsrc4[(size_t)b * 512 + t];
    float4 rv = make_float4(0.f, 0.f, 0.f, 0.f);
    if (res) rv = ((const float4*)res)[(size_t)b * 512 + t];
    if (t < 128) {
        float s_ = 0.f, q_ = 0.f;
        #pragma unroll
        for (int rr = 0; rr < NREP; rr++) {
            s_ += stats_in[rr * 256 + t];
            q_ += stats_in[rr * 256 + 128 + t];
        }
        const float K = 1.f / 65536.f;
        float mean = s_ * K;
        float varv = q_ * K - mean * mean;
        bnm[t] = mean;
        bnsc[t] = rsqrtf(varv + 1e-5f) * bn_g[t];
        bnbb[t] = bn_b[t];
    } else if (t < 256) {
        vtl[t - 128] = vt[t - 128];
    }
    int c4 = (4 * t) & 127;
    int r0 = t >> 5;
    int rg = restored[r0];
    __syncthreads();                 // single prologue barrier
    int w = t >> 6, lane = t & 63;
    int mn = lane & 15, kq = (lane >> 4) << 3, qr = (lane >> 4) << 2;
    float4 hv;                       // held until kernel end
    // -------- phase 0: bn/relu + residual -> regs + LDS staging (no store)
    {
        float4 m4 = *(const float4*)&bnm[c4];
        float4 sc4 = *(const float4*)&bnsc[c4];
        float4 bb4 = *(const float4*)&bnbb[c4];
        hv.x = fmaxf((sv.x - m4.x) * sc4.x + bb4.x, 0.f) + rv.x;
        hv.y = fmaxf((sv.y - m4.y) * sc4.y + bb4.y, 0.f) + rv.y;
        hv.z = fmaxf((sv.z - m4.z) * sc4.z + bb4.z, 0.f) + rv.z;
        hv.w = fmaxf((sv.w - m4.w) * sc4.w + bb4.w, 0.f) + rv.w;
        uint2 hh, ll;
        splitbf4(hv, hh, ll);
        *(uint2*)&xch[rg][c4] = hh;
        *(uint2*)&xcl[rg][c4] = ll;
    }
    __syncthreads();
    // -------- phase 1: g-conv + p-conv MFMA (8 tiles over 8 waves)
    {
        int conv = w >> 2;          // 0=g, 1=p
        int mt = w & 3;
        int wbase = (conv == 0) ? 0 : 128;
        const unsigned short* aph = nlwh + (size_t)(wbase + mt * 16 + mn) * 128 + kq;
        const unsigned short* apl = nlwl + (size_t)(wbase + mt * 16 + mn) * 128 + kq;
        f32x4 acc = {0.f, 0.f, 0.f, 0.f};
        #pragma unroll
        for (int k = 0; k < 4; k++) {
            short8 bh = *(const short8*)&xch[mn][k * 32 + kq];
            short8 bl = *(const short8*)&xcl[mn][k * 32 + kq];
            acc = mfma_split(*(const short8*)(aph + k * 32), *(const short8*)(apl + k * 32),
                             bh, bl, acc);
        }
        const float* biasp = (conv == 0) ? g_b : p_b;
        #pragma unroll
        for (int r = 0; r < 4; r++) {
            int o = mt * 16 + qr + r;
            CG(conv, o, mn) = acc[r] + biasp[o];
        }
    }
    __syncthreads();
    // -------- phase 2+3 merged: gx pool (all), pv via wave0, tv via wave1
    {
        int c = t >> 3, w2 = t & 7;
        gx[c][w2] = fmaxf(CG(0, c, 2 * w2), CG(0, c, 2 * w2 + 1));
        if (t < 64) {
            int ch = t >> 3;
            float ss = 0.f;
            for (int cc = ch * 8; cc < ch * 8 + 8; cc++)
                ss += fmaxf(CG(1, cc, 2 * w2), CG(1, cc, 2 * w2 + 1)) * cpw[64 + cc];
            ss += __shfl_xor(ss, 8);
            ss += __shfl_xor(ss, 16);
            ss += __shfl_xor(ss, 32);
            if (t < 8) pv[t] = ss;
        } else if (t < 128) {
            int u = t - 64, j = u & 15, ch = u >> 4;
            float ss = 0.f;
            int c0 = ch * 32;
            for (int cc = c0; cc < c0 + 32; cc += 2) {
                unsigned hh = *(const unsigned*)&xch[j][cc];
                unsigned ll = *(const unsigned*)&xcl[j][cc];
                float v0 = bfpair((unsigned short)hh, (unsigned short)ll);
                float v1 = bfpair((unsigned short)(hh >> 16), (unsigned short)(ll >> 16));
                ss += vtl[cc] * v0 + vtl[cc + 1] * v1;
            }
            ss += __shfl_xor(ss, 16);
            ss += __shfl_xor(ss, 32);
            if (u < 16) tv[u] = ss + ctp[0];
        }
    }
    __syncthreads();
    // -------- phase 4: y (1024 units over 512 threads)
    #pragma unroll
    for (int u2 = 0; u2 < 2; u2++) {
        int u = t + u2 * 512;
        int j = u >> 6, c = u & 63;
        float ss = 0.f;
        #pragma unroll
        for (int w2 = 0; w2 < 8; w2++)
            ss += fmaxf(tv[j] + pv[w2], 0.f) * gx[c][w2];
        unsigned short h2, l2;
        splitbf(ss * 0.125f, h2, l2);
        ybh[j][c] = h2; ybl[j][c] = l2;
    }
    __syncthreads();
    // -------- phase 5: Wy MFMA (8 tiles over 8 waves)
    {
        int mt = w;
        short8 byh0 = *(const short8*)&ybh[mn][kq];
        short8 byh1 = *(const short8*)&ybh[mn][32 + kq];
        short8 byl0 = *(const short8*)&ybl[mn][kq];
        short8 byl1 = *(const short8*)&ybl[mn][32 + kq];
        const unsigned short* aph = nlWh + (size_t)(mt * 16 + mn) * 64 + kq;
        const unsigned short* apl = nlWl + (size_t)(mt * 16 + mn) * 64 + kq;
        f32x4 acc = {0.f, 0.f, 0.f, 0.f};
        acc = mfma_split(*(const short8*)aph, *(const short8*)apl, byh0, byl0, acc);
        acc = mfma_split(*(const short8*)(aph + 32), *(const short8*)(apl + 32), byh1, byl1, acc);
        #pragma unroll
        for (int r = 0; r < 4; r++) {
            int o = mt * 16 + qr + r;
            WYL(o, mn) = acc[r] + W_b[o];
        }
    }
    __syncthreads();
    // -------- phase 6a: stats reduction from WYL (LDS only, no stores yet)
    {
        int c = t & 127;
        float ss = 0.f, qq = 0.f;
        #pragma unroll
        for (int u2 = 0; u2 < 4; u2++) {
            int idx = t + u2 * 512;
            float v = WYL(c, idx >> 7);
            ss += v; qq += v * v;
        }
        redS[t] = ss; redQ[t] = qq;
    }
    __syncthreads();
    // -------- phase 6b: atomics + ALL global stores past the last barrier
    {
        float* so = wst + (b & (NREP - 1)) * 256;
        if (t < 128) {
            float s4 = redS[t] + redS[t + 128] + redS[t + 256] + redS[t + 384];
            float q4 = redQ[t] + redQ[t + 128] + redQ[t + 256] + redQ[t + 384];
            atomicAdd(&so[t], s4);
            atomicAdd(&so[128 + t], q4);
        }
        int c = t & 127;
        #pragma unroll
        for (int u2 = 0; u2 < 4; u2++) {
            int idx = t + u2 * 512;
            wydst[(size_t)b * 2048 + idx] = WYL(c, idx >> 7);
        }
        ((float4*)hdst)[(size_t)b * 512 + t] = hv;
    }
}

// ---------------------------------------------------------------- gconv out (128->3), fused nl_b
__global__ __launch_bounds__(256) void gconv_out_kernel(
        const float* __restrict__ h, const float* __restrict__ wy,
        const float* __restrict__ stats_in,
        const float* __restrict__ nlg, const float* __restrict__ nlb,
        const int* __restrict__ restored,
        const float* __restrict__ W,
        const float* __restrict__ bias, const float* __restrict__ off,
        const float* __restrict__ diag, float* __restrict__ out) {
    __shared__ float hs[16][132];
    __shared__ float gsv[16][132];
    __shared__ float offs[256];
    __shared__ float p0[48][4], p1[48][4];
    int b = blockIdx.x, t = threadIdx.x;
    offs[t] = off[t];
    float* hsf = &hs[0][0];
    {
        float ssum = 0.f;
        #pragma unroll
        for (int rr = 0; rr < NREP; rr++) ssum += stats_in[rr * 256 + t];
        hsf[t] = ssum;
    }
    __syncthreads();
    int c = t & 127;
    float mean, inv, bbv;
    {
        const float K = 1.f / 65536.f;
        mean = hsf[c] * K;
        float varv = hsf[128 + c] * K - mean * mean;
        inv = rsqrtf(varv + 1e-5f) * nlg[c];
        bbv = nlb[c];
    }
    __syncthreads();
    {
        for (int idx = t; idx < 2048; idx += 256) {
            int r = idx >> 7;
            float wval = wy[(size_t)b * 2048 + restored[r] * 128 + c];
            hs[r][c] = (wval - mean) * inv + bbv + h[(size_t)b * 2048 + idx];
        }
    }
    __syncthreads();
    for (int idx = t; idx < 2048; idx += 256) {
        int i = idx >> 7, f = idx & 127;
        float g = 0.f;
        #pragma unroll
        for (int j = 0; j < 16; j++) g += offs[i * 16 + j] * hs[j][f];
        gsv[i][f] = g;
    }
    __syncthreads();
    if (t < 192) {
        int oid = t >> 2, chunk = t & 3;
        int i = oid / 3, o = oid % 3;
        float a0 = 0.f, a1 = 0.f;
        int f0 = chunk * 32;
        for (int f = f0; f < f0 + 32; f++) {
            a0 += hs[i][f] * W[f * 3 + o];
            a1 += gsv[i][f] * W[384 + f * 3 + o];
        }
        p0[oid][chunk] = a0; p1[oid][chunk] = a1;
    }
    __syncthreads();
    if (t < 48) {
        int i = t / 3, o = t % 3;
        float a0 = p0[t][0] + p0[t][1] + p0[t][2] + p0[t][3];
        float a1 = p1[t][0] + p1[t][1] + p1[t][2] + p1[t][3];
        out[(size_t)b * 48 + t] = diag[i] * a0 + a1 + bias[o];
    }
}

// ================================================================ launch
extern "C" void kernel_launch(void* const* d_in, const int* in_sizes, int n_in,
                              void* d_out, int out_size, void* d_ws, size_t ws_size,
                              hipStream_t stream) {
    (void)n_in; (void)out_size; (void)ws_size;
    const float* x        = (const float*)d_in[0];
    const float* gc_in_W  = (const float*)d_in[1];
    const float* gc_in_e  = (const float*)d_in[2];
    const float* gc_in_b  = (const float*)d_in[3];
    const float* bn_in_g  = (const float*)d_in[4];
    const float* bn_in_b  = (const float*)d_in[5];
    const float* W_res    = (const float*)d_in[6];
    const float* e_res    = (const float*)d_in[7];
    const float* b_res    = (const float*)d_in[8];
    const float* bng_res  = (const float*)d_in[9];
    const float* bnb_res  = (const float*)d_in[10];
    const float* nl_g_w   = (const float*)d_in[11];
    const float* nl_g_b   = (const float*)d_in[12];
    const float* nl_t_w   = (const float*)d_in[13];
    const float* nl_t_b   = (const float*)d_in[14];
    const float* nl_p_w   = (const float*)d_in[15];
    const float* nl_p_b   = (const float*)d_in[16];
    const float* nl_cp_w  = (const float*)d_in[17];
    const float* nl_W_w   = (const float*)d_in[18];
    const float* nl_W_b   = (const float*)d_in[19];
    const float* nl_bn_g  = (const float*)d_in[20];
    const float* nl_bn_b  = (const float*)d_in[21];
    const float* gc_out_W = (const float*)d_in[22];
    const float* gc_out_e = (const float*)d_in[23];
    const float* gc_out_b = (const float*)d_in[24];
    const int*   mask_rows = (const int*)d_in[25];
    const int*   mask_cols = (const int*)d_in[26];
    const int*   restored  = (const int*)d_in[28];
    int nnz = in_sizes[2];

    float* ws       = (float*)d_ws;
    float* off_all  = ws;                  // 0..2560
    float* diag_all = ws + 2560;           // ..2720
    float* stats    = ws + 2720;           // 14 x 4096 -> ..60064
    float* vt       = ws + 63664;          // 5 x 128
    float* ct       = ws + 64304;          // 5
    unsigned short* Wbh  = (unsigned short*)(ws + 65536);
    unsigned short* Wbl  = Wbh + WB_N;
    unsigned short* nlwh = Wbl + WB_N;
    unsigned short* nlwl = nlwh + NLW_N;
    unsigned short* nlWh = nlwl + NLW_N;
    unsigned short* nlWl = nlWh + NLWW_N;  // ends at float 491520
    float* Z = ws + 491520;
    float* T = Z + ELEMS;

    // fused head: prep_w + adj + prep_vt + stats-zero in ONE dispatch
    prep_all_kernel<<<PREPW_BLKS + 15 + 14, 256, 0, stream>>>(
        W_res, nl_g_w, nl_t_w, nl_p_w, nl_W_w,
        Wbh, Wbl, nlwh, nlwl, nlWh, nlWl,
        gc_in_e, e_res, gc_out_e, mask_rows, mask_cols, nnz,
        off_all, diag_all,
        nl_t_b, nl_cp_w, vt, ct, stats);

    // t0 -> T, slot 0
    gconv_in_kernel<<<B, 256, 0, stream>>>(x, gc_in_W, gc_in_b, off_all, diag_all,
                                           T, stats);
    // nonlocal 0: h0 -> Z; wy -> T, slot 1
    nl_a_kernel<<<B, 512, 0, stream>>>(T, stats, bn_in_g, bn_in_b, nullptr,
                                       nlwh, nlwl, nl_g_b, nl_p_b, nl_cp_w,
                                       vt, ct, nlWh, nlWl, nl_W_b, restored,
                                       Z, T, stats + SLOT);

    int sl = 1;
    for (int i = 0; i < NLAYERS; i++) {
        int l0 = 2 * i, l1 = 2 * i + 1, li = i + 1;
        // gconv1 + fused nl_b: z -> Z; t1 -> T, slot sl+1
        gconv_mfma_kernel<<<2048, 256, 0, stream>>>(
            Z, T, stats + (size_t)sl * SLOT,
            nl_bn_g + i * 128, nl_bn_b + i * 128, restored, Z,
            Wbh + (size_t)l0 * 32768, Wbl + (size_t)l0 * 32768, b_res + l0 * 128,
            off_all + (1 + l0) * 256, diag_all + (1 + l0) * 16, T,
            stats + (size_t)(sl + 1) * SLOT);
        // gconv2: t2 -> T, slot sl+2
        gconv_mfma_kernel<<<2048, 256, 0, stream>>>(
            T, nullptr, stats + (size_t)(sl + 1) * SLOT,
            bng_res + l0 * 128, bnb_res + l0 * 128, nullptr, nullptr,
            Wbh + (size_t)l1 * 32768, Wbl + (size_t)l1 * 32768, b_res + l1 * 128,
            off_all + (1 + l1) * 256, diag_all + (1 + l1) * 16, T,
            stats + (size_t)(sl + 2) * SLOT);
        // nl_a: h -> Z; wy -> T, slot sl+3
        nl_a_kernel<<<B, 512, 0, stream>>>(
            T, stats + (size_t)(sl + 2) * SLOT,
            bng_res + l1 * 128, bnb_res + l1 * 128, Z,
            nlwh + li * 24576, nlwl + li * 24576,
            nl_g_b + li * 64, nl_p_b + li * 64, nl_cp_w + li * 128,
            vt + li * 128, ct + li, nlWh + li * 8192, nlWl + li * 8192,
            nl_W_b + li * 128, restored, Z, T,
            stats + (size_t)(sl + 3) * SLOT);
        sl += 3;
    }
    gconv_out_kernel<<<B, 256, 0, stream>>>(Z, T, stats + (size_t)sl * SLOT,
                                            nl_bn_g + NLAYERS * 128, nl_bn_b + NLAYERS * 128,
                                            restored, gc_out_W, gc_out_b,
                                            off_all + 9 * 256, diag_all + 9 * 16,
                                            (float*)d_out);
}

// Round 8
// 873.695 us; speedup vs baseline: 2.6230x; 2.6230x over previous
//
#include <hip/hip_runtime.h>

#define B 4096
#define J 16
#define HID 128
#define INTER 64
#define NLAYERS 4
#define NEGV -9000000000000000.0f
#define ELEMS ((size_t)B*16*128)
#define NREP 16
#define SLOT 4096

typedef __attribute__((ext_vector_type(8))) short short8;
typedef __attribute__((ext_vector_type(4))) float f32x4;

static __device__ __forceinline__ unsigned short f2bf(float x) {
    unsigned u = __float_as_uint(x);
    unsigned r = u + 0x7fffu + ((u >> 16) & 1u);
    return (unsigned short)(r >> 16);
}
static __device__ __forceinline__ void splitbf(float x, unsigned short& h, unsigned short& l) {
    h = f2bf(x);
    float hf = __uint_as_float((unsigned)h << 16);
    l = f2bf(x - hf);
}
static __device__ __forceinline__ void splitbf4(float4 v, uint2& hh, uint2& ll) {
    unsigned short h0,l0,h1,l1,h2,l2,h3,l3;
    splitbf(v.x,h0,l0); splitbf(v.y,h1,l1); splitbf(v.z,h2,l2); splitbf(v.w,h3,l3);
    hh = make_uint2((unsigned)h0 | ((unsigned)h1<<16), (unsigned)h2 | ((unsigned)h3<<16));
    ll = make_uint2((unsigned)l0 | ((unsigned)l1<<16), (unsigned)l2 | ((unsigned)l3<<16));
}
static __device__ __forceinline__ f32x4 mfma16(short8 a, short8 b, f32x4 c) {
    return __builtin_amdgcn_mfma_f32_16x16x32_bf16(a, b, c, 0, 0, 0);
}
static __device__ __forceinline__ f32x4 mfma_split(short8 ah, short8 al,
                                                   short8 bh, short8 bl, f32x4 acc) {
    acc = mfma16(ah, bh, acc);
    acc = mfma16(ah, bl, acc);
    acc = mfma16(al, bh, acc);
    return acc;
}
static __device__ __forceinline__ float bfpair(unsigned short h, unsigned short l) {
    return __uint_as_float((unsigned)h << 16) + __uint_as_float((unsigned)l << 16);
}

// ---------------------------------------------------------------- fused prep
#define WB_N   262144
#define NLW_N  122880
#define NLWW_N 40960
#define PREPW_BLKS 1664   // (WB_N+NLW_N+NLWW_N)/256 exactly
__global__ __launch_bounds__(256) void prep_all_kernel(
        const float* __restrict__ W_res,
        const float* __restrict__ g_w, const float* __restrict__ t_w,
        const float* __restrict__ p_w, const float* __restrict__ W_w,
        unsigned short* __restrict__ Wbh, unsigned short* __restrict__ Wbl,
        unsigned short* __restrict__ nlwh, unsigned short* __restrict__ nlwl,
        unsigned short* __restrict__ nlWh, unsigned short* __restrict__ nlWl,
        const float* __restrict__ e_in, const float* __restrict__ e_res,
        const float* __restrict__ e_out,
        const int* __restrict__ rows, const int* __restrict__ cols, int nnz,
        float* __restrict__ off_all, float* __restrict__ diag_all,
        const float* __restrict__ t_b, const float* __restrict__ cp_w,
        float* __restrict__ vt, float* __restrict__ ct,
        float* __restrict__ stats) {
    int blk = blockIdx.x, t = threadIdx.x;
    if (blk < PREPW_BLKS) {
        int i = blk * 256 + t;
        unsigned short h, l;
        if (i < WB_N) {
            int lay = i >> 15, rem = i & 32767, n = rem >> 8, k = rem & 255;
            int d = k >> 7, f = k & 127;
            splitbf(W_res[(((lay << 1) | d) * 128 + f) * 128 + n], h, l);
            Wbh[i] = h; Wbl[i] = l;
        } else if (i < WB_N + NLW_N) {
            int j = i - WB_N;
            int lay = j / 24576, r2 = j % 24576;
            int conv = r2 >> 13, oc = r2 & 8191;
            const float* src = conv == 0 ? g_w : conv == 1 ? t_w : p_w;
            splitbf(src[lay * 8192 + oc], h, l);
            nlwh[j] = h; nlwl[j] = l;
        } else {
            int j = i - WB_N - NLW_N;
            splitbf(W_w[j], h, l);
            nlWh[j] = h; nlWl[j] = l;
        }
    } else if (blk < PREPW_BLKS + 10) {
        if (t < 16) {
            int m = blk - PREPW_BLKS;
            int i = t;
            const float* e = (m == 0) ? e_in : (m <= 8) ? e_res + (size_t)(m - 1) * nnz : e_out;
            float l[16];
            for (int j = 0; j < 16; j++) l[j] = NEGV;
            for (int k = 0; k < nnz; k++)
                if (rows[k] == i) l[cols[k]] = e[k];
            float mx = l[0];
            for (int j = 1; j < 16; j++) mx = fmaxf(mx, l[j]);
            float ex[16], s = 0.f;
            for (int j = 0; j < 16; j++) { ex[j] = expf(l[j] - mx); s += ex[j]; }
            float inv = 1.f / s;
            for (int j = 0; j < 16; j++) {
                float a = ex[j] * inv;
                if (j == i) { diag_all[m * 16 + i] = a; a = 0.f; }
                off_all[m * 256 + i * 16 + j] = a;
            }
        }
    } else if (blk < PREPW_BLKS + 15) {
        if (t < 128) {
            int l = blk - PREPW_BLKS - 10, c = t;
            float s = 0.f;
            for (int c2 = 0; c2 < 64; c2++)
                s += cp_w[l * 128 + c2] * t_w[(l * 64 + c2) * 128 + c];
            vt[l * 128 + c] = s;
            if (c == 0) {
                float s2 = 0.f;
                for (int c2 = 0; c2 < 64; c2++) s2 += cp_w[l * 128 + c2] * t_b[l * 64 + c2];
                ct[l] = s2;
            }
        }
    } else {
        int sl_ = blk - PREPW_BLKS - 15;   // 0..13
        float* dst = stats + (size_t)sl_ * SLOT;
        #pragma unroll
        for (int u = 0; u < 16; u++) dst[t + u * 256] = 0.f;
    }
}

// ---------------------------------------------------------------- gconv in (F=2)
__global__ __launch_bounds__(256) void gconv_in_kernel(
        const float* __restrict__ x, const float* __restrict__ W,
        const float* __restrict__ bias, const float* __restrict__ off,
        const float* __restrict__ diag, float* __restrict__ out,
        float* __restrict__ stats_out) {
    __shared__ float xs[16][2];
    __shared__ float gs[16][2];
    __shared__ float red[512];
    int b = blockIdx.x, t = threadIdx.x;
    if (t < 32) xs[t >> 1][t & 1] = x[b * 32 + t];
    __syncthreads();
    if (t < 32) {
        int i = t >> 1, f = t & 1;
        float g = 0.f;
        #pragma unroll
        for (int j = 0; j < 16; j++) g += off[i * 16 + j] * xs[j][f];
        gs[i][f] = g;
    }
    __syncthreads();
    int o = t & 127;
    float w00 = W[o], w01 = W[128 + o], w10 = W[256 + o], w11 = W[384 + o], bo = bias[o];
    float s = 0.f, q = 0.f;
    float vals[8];
    #pragma unroll
    for (int u = 0; u < 8; u++) {
        int idx = t + u * 256;
        int i = idx >> 7;
        float v = diag[i] * (xs[i][0] * w00 + xs[i][1] * w01)
                + gs[i][0] * w10 + gs[i][1] * w11 + bo;
        vals[u] = v;
        s += v; q += v * v;
    }
    red[t] = s; red[256 + t] = q;
    __syncthreads();
    float* so = stats_out + (b & (NREP - 1)) * 256;
    if (t < 128) {
        atomicAdd(&so[t], red[t] + red[t + 128]);
        atomicAdd(&so[128 + t], red[256 + t] + red[256 + t + 128]);
    }
    #pragma unroll
    for (int u = 0; u < 8; u++)
        out[(size_t)b * 2048 + t + u * 256] = vals[u];
}

// ---------------------------------------------------------------- gconv 128->128
// R6-verified version (58 us/dispatch): zdst stored in phase 0, inline stats
// atomics. DO NOT defer stores across the s-loop: R7 showed 16 VGPRs of
// deferred state under tightened launch_bounds spills to scratch ->
// FETCH/WRITE x8 and 250 us/dispatch.
__global__ __launch_bounds__(256) void gconv_mfma_kernel(
        const float* src, const float* wy,
        const float* __restrict__ stats_in,
        const float* __restrict__ bn_g, const float* __restrict__ bn_b,
        const int* __restrict__ restored, float* zdst,
        const unsigned short* __restrict__ Wbh,
        const unsigned short* __restrict__ Wbl,
        const float* __restrict__ bias,
        const float* __restrict__ off, const float* __restrict__ diag,
        float* dst, float* __restrict__ stats_out) {
    __shared__ float hraw[16][132];
    __shared__ __align__(16) unsigned short ksh[16][264];
    __shared__ __align__(16) unsigned short ksl[16][264];
    __shared__ float offs[256];
    __shared__ float diags[16];
    int t = threadIdx.x;
    offs[t] = off[t];
    if (t < 16) diags[t] = diag[t];
    float* hrawf = &hraw[0][0];
    {
        float ssum = 0.f;
        #pragma unroll
        for (int rr = 0; rr < NREP; rr++) ssum += stats_in[rr * 256 + t];
        hrawf[t] = ssum;
    }
    int c4 = (4 * t) & 127;
    int r0 = t >> 5;
    int ro0 = 0, ro1 = 0;
    if (wy) { ro0 = restored[r0]; ro1 = restored[r0 + 8]; }
    int b0 = blockIdx.x;
    const float4* src4 = (const float4*)src;
    const float4* wy4  = (const float4*)wy;
    float4 sv0 = src4[(size_t)b0 * 512 + t];
    float4 sv1 = src4[(size_t)b0 * 512 + 256 + t];
    float4 wv0 = make_float4(0,0,0,0), wv1 = make_float4(0,0,0,0);
    if (wy) {
        wv0 = wy4[(size_t)b0 * 512 + ro0 * 32 + (c4 >> 2)];
        wv1 = wy4[(size_t)b0 * 512 + ro1 * 32 + (c4 >> 2)];
    }
    __syncthreads();
    float4 m4, sc4, bb4;
    {
        const float K = 1.f / 65536.f;
        float4 g4 = *(const float4*)&bn_g[c4];
        bb4 = *(const float4*)&bn_b[c4];
        float m0 = hrawf[c4]     * K, m1 = hrawf[c4 + 1] * K;
        float m2 = hrawf[c4 + 2] * K, m3 = hrawf[c4 + 3] * K;
        float i0 = rsqrtf(hrawf[128 + c4]     * K - m0 * m0 + 1e-5f);
        float i1 = rsqrtf(hrawf[128 + c4 + 1] * K - m1 * m1 + 1e-5f);
        float i2 = rsqrtf(hrawf[128 + c4 + 2] * K - m2 * m2 + 1e-5f);
        float i3 = rsqrtf(hrawf[128 + c4 + 3] * K - m3 * m3 + 1e-5f);
        m4 = make_float4(m0, m1, m2, m3);
        sc4 = make_float4(i0 * g4.x, i1 * g4.y, i2 * g4.z, i3 * g4.w);
    }
    __syncthreads();
    int wv_ = t >> 6, lane = t & 63;
    int mn = lane & 15, kq = (lane >> 4) << 3, qr = (lane >> 4) << 2;

    for (int s = 0; s < 2; s++) {
        int bb_ = blockIdx.x + s * 2048;
        {
            float4 v = sv0;
            if (wy) {
                v.x += (wv0.x - m4.x) * sc4.x + bb4.x;
                v.y += (wv0.y - m4.y) * sc4.y + bb4.y;
                v.z += (wv0.z - m4.z) * sc4.z + bb4.z;
                v.w += (wv0.w - m4.w) * sc4.w + bb4.w;
                ((float4*)zdst)[(size_t)bb_ * 512 + t] = v;
            } else {
                v.x = fmaxf((v.x - m4.x) * sc4.x + bb4.x, 0.f);
                v.y = fmaxf((v.y - m4.y) * sc4.y + bb4.y, 0.f);
                v.z = fmaxf((v.z - m4.z) * sc4.z + bb4.z, 0.f);
                v.w = fmaxf((v.w - m4.w) * sc4.w + bb4.w, 0.f);
            }
            *(float4*)&hraw[r0][c4] = v;
            v = sv1;
            if (wy) {
                v.x += (wv1.x - m4.x) * sc4.x + bb4.x;
                v.y += (wv1.y - m4.y) * sc4.y + bb4.y;
                v.z += (wv1.z - m4.z) * sc4.z + bb4.z;
                v.w += (wv1.w - m4.w) * sc4.w + bb4.w;
                ((float4*)zdst)[(size_t)bb_ * 512 + 256 + t] = v;
            } else {
                v.x = fmaxf((v.x - m4.x) * sc4.x + bb4.x, 0.f);
                v.y = fmaxf((v.y - m4.y) * sc4.y + bb4.y, 0.f);
                v.z = fmaxf((v.z - m4.z) * sc4.z + bb4.z, 0.f);
                v.w = fmaxf((v.w - m4.w) * sc4.w + bb4.w, 0.f);
            }
            *(float4*)&hraw[r0 + 8][c4] = v;
        }
        if (s == 0) {
            int b1 = blockIdx.x + 2048;
            sv0 = src4[(size_t)b1 * 512 + t];
            sv1 = src4[(size_t)b1 * 512 + 256 + t];
            if (wy) {
                wv0 = wy4[(size_t)b1 * 512 + ro0 * 32 + (c4 >> 2)];
                wv1 = wy4[(size_t)b1 * 512 + ro1 * 32 + (c4 >> 2)];
            }
        }
        __syncthreads();
        for (int u = t; u < 512; u += 256) {
            int i = u >> 5, f4 = (u & 31) << 2;
            float4 hv = *(const float4*)&hraw[i][f4];
            float4 g = make_float4(0.f, 0.f, 0.f, 0.f);
            #pragma unroll
            for (int j = 0; j < 16; j++) {
                float w = offs[i * 16 + j];
                float4 hj = *(const float4*)&hraw[j][f4];
                g.x += w * hj.x; g.y += w * hj.y; g.z += w * hj.z; g.w += w * hj.w;
            }
            float d = diags[i];
            uint2 hh, ll;
            splitbf4(make_float4(d * hv.x, d * hv.y, d * hv.z, d * hv.w), hh, ll);
            *(uint2*)&ksh[i][f4] = hh;
            *(uint2*)&ksl[i][f4] = ll;
            splitbf4(g, hh, ll);
            *(uint2*)&ksh[i][128 + f4] = hh;
            *(uint2*)&ksl[i][128 + f4] = ll;
        }
        __syncthreads();
        int n0 = wv_ << 5;
        f32x4 acc0 = {0.f, 0.f, 0.f, 0.f}, acc1 = {0.f, 0.f, 0.f, 0.f};
        const unsigned short* wh0 = Wbh + (size_t)(n0 + mn) * 256 + kq;
        const unsigned short* wl0 = Wbl + (size_t)(n0 + mn) * 256 + kq;
        #pragma unroll
        for (int k = 0; k < 8; k++) {
            int k0 = k << 5;
            short8 ah = *(const short8*)&ksh[mn][k0 + kq];
            short8 al = *(const short8*)&ksl[mn][k0 + kq];
            acc0 = mfma_split(ah, al, *(const short8*)(wh0 + k0), *(const short8*)(wl0 + k0), acc0);
            acc1 = mfma_split(ah, al, *(const short8*)(wh0 + 4096 + k0), *(const short8*)(wl0 + 4096 + k0), acc1);
        }
        float bias0 = bias[n0 + mn], bias1 = bias[n0 + 16 + mn];
        float s0 = 0.f, q0 = 0.f, s1 = 0.f, q1 = 0.f;
        #pragma unroll
        for (int r = 0; r < 4; r++) {
            int row = qr + r;
            float v0 = acc0[r] + bias0;
            float v1 = acc1[r] + bias1;
            dst[(size_t)bb_ * 2048 + row * 128 + n0 + mn] = v0;
            dst[(size_t)bb_ * 2048 + row * 128 + n0 + 16 + mn] = v1;
            s0 += v0; q0 += v0 * v0; s1 += v1; q1 += v1 * v1;
        }
        s0 += __shfl_xor(s0, 16); s0 += __shfl_xor(s0, 32);
        q0 += __shfl_xor(q0, 16); q0 += __shfl_xor(q0, 32);
        s1 += __shfl_xor(s1, 16); s1 += __shfl_xor(s1, 32);
        q1 += __shfl_xor(q1, 16); q1 += __shfl_xor(q1, 32);
        float* so = stats_out + (bb_ & (NREP - 1)) * 256;
        if (lane < 16) {
            atomicAdd(&so[n0 + mn], s0);
            atomicAdd(&so[128 + n0 + mn], q0);
            atomicAdd(&so[n0 + 16 + mn], s1);
            atomicAdd(&so[128 + n0 + 16 + mn], q1);
        }
        if (s == 0) __syncthreads();
    }
}

// ---------------------------------------------------------------- nonlocal A
// 512 threads, ONE sample (grid 4096). R7-verified store-motion (~34 us,
// was 69): single prologue barrier (t<128 computes BN params straight from
// stats columns), h value held in 4 VGPRs and stored at kernel end, phase-6
// wydst stores moved past the stats barrier. No global store precedes any
// mid-kernel barrier -> no vmcnt(0) store drains. Only 4 held VGPRs (hv) —
// small enough to avoid the R5/R7 scratch-spill pathology.
#define CG(conv, o, j) cgbuf[((conv) * 64 + (o)) * 17 + (j)]
#define WYL(o, j)      cgbuf[(o) * 17 + (j)]
__global__ __launch_bounds__(512, 8) void nl_a_kernel(
        const float* tsrc, const float* __restrict__ stats_in,
        const float* __restrict__ bn_g, const float* __restrict__ bn_b,
        const float* res,
        const unsigned short* __restrict__ nlwh,
        const unsigned short* __restrict__ nlwl,
        const float* __restrict__ g_b, const float* __restrict__ p_b,
        const float* __restrict__ cpw,
        const float* __restrict__ vt, const float* __restrict__ ctp,
        const unsigned short* __restrict__ nlWh,
        const unsigned short* __restrict__ nlWl,
        const float* __restrict__ W_b,
        const int* __restrict__ restored,
        float* hdst, float* wydst, float* __restrict__ wst) {
    __shared__ __align__(16) unsigned short xch[16][136];
    __shared__ __align__(16) unsigned short xcl[16][136];
    __shared__ float cgbuf[2176];
    __shared__ float gx[64][9];
    __shared__ float tv[16], pv[8];
    __shared__ float vtl[128];
    __shared__ __align__(16) float bnm[128], bnsc[128], bnbb[128];
    __shared__ __align__(16) unsigned short ybh[16][72];
    __shared__ __align__(16) unsigned short ybl[16][72];
    __shared__ float redS[512], redQ[512];
    int t = threadIdx.x, b = blockIdx.x;
    const float4* tsrc4 = (const float4*)tsrc;
    // issue tensor loads early; they resolve while stats reduce
    float4 sv = tsrc4[(size_t)b * 512 + t];
    float4 rv = make_float4(0.f, 0.f, 0.f, 0.f);
    if (res) rv = ((const float4*)res)[(size_t)b * 512 + t];
    if (t < 128) {
        float s_ = 0.f, q_ = 0.f;
        #pragma unroll
        for (int rr = 0; rr < NREP; rr++) {
            s_ += stats_in[rr * 256 + t];
            q_ += stats_in[rr * 256 + 128 + t];
        }
        const float K = 1.f / 65536.f;
        float mean = s_ * K;
        float varv = q_ * K - mean * mean;
        bnm[t] = mean;
        bnsc[t] = rsqrtf(varv + 1e-5f) * bn_g[t];
        bnbb[t] = bn_b[t];
    } else if (t < 256) {
        vtl[t - 128] = vt[t - 128];
    }
    int c4 = (4 * t) & 127;
    int r0 = t >> 5;
    int rg = restored[r0];
    __syncthreads();                 // single prologue barrier
    int w = t >> 6, lane = t & 63;
    int mn = lane & 15, kq = (lane >> 4) << 3, qr = (lane >> 4) << 2;
    float4 hv;                       // held until kernel end (4 VGPRs only)
    // -------- phase 0: bn/relu + residual -> regs + LDS staging (no store)
    {
        float4 m4 = *(const float4*)&bnm[c4];
        float4 sc4 = *(const float4*)&bnsc[c4];
        float4 bb4 = *(const float4*)&bnbb[c4];
        hv.x = fmaxf((sv.x - m4.x) * sc4.x + bb4.x, 0.f) + rv.x;
        hv.y = fmaxf((sv.y - m4.y) * sc4.y + bb4.y, 0.f) + rv.y;
        hv.z = fmaxf((sv.z - m4.z) * sc4.z + bb4.z, 0.f) + rv.z;
        hv.w = fmaxf((sv.w - m4.w) * sc4.w + bb4.w, 0.f) + rv.w;
        uint2 hh, ll;
        splitbf4(hv, hh, ll);
        *(uint2*)&xch[rg][c4] = hh;
        *(uint2*)&xcl[rg][c4] = ll;
    }
    __syncthreads();
    // -------- phase 1: g-conv + p-conv MFMA (8 tiles over 8 waves)
    {
        int conv = w >> 2;          // 0=g, 1=p
        int mt = w & 3;
        int wbase = (conv == 0) ? 0 : 128;
        const unsigned short* aph = nlwh + (size_t)(wbase + mt * 16 + mn) * 128 + kq;
        const unsigned short* apl = nlwl + (size_t)(wbase + mt * 16 + mn) * 128 + kq;
        f32x4 acc = {0.f, 0.f, 0.f, 0.f};
        #pragma unroll
        for (int k = 0; k < 4; k++) {
            short8 bh = *(const short8*)&xch[mn][k * 32 + kq];
            short8 bl = *(const short8*)&xcl[mn][k * 32 + kq];
            acc = mfma_split(*(const short8*)(aph + k * 32), *(const short8*)(apl + k * 32),
                             bh, bl, acc);
        }
        const float* biasp = (conv == 0) ? g_b : p_b;
        #pragma unroll
        for (int r = 0; r < 4; r++) {
            int o = mt * 16 + qr + r;
            CG(conv, o, mn) = acc[r] + biasp[o];
        }
    }
    __syncthreads();
    // -------- phase 2+3 merged: gx pool (all), pv via wave0, tv via wave1
    {
        int c = t >> 3, w2 = t & 7;
        gx[c][w2] = fmaxf(CG(0, c, 2 * w2), CG(0, c, 2 * w2 + 1));
        if (t < 64) {
            int ch = t >> 3;
            float ss = 0.f;
            for (int cc = ch * 8; cc < ch * 8 + 8; cc++)
                ss += fmaxf(CG(1, cc, 2 * w2), CG(1, cc, 2 * w2 + 1)) * cpw[64 + cc];
            ss += __shfl_xor(ss, 8);
            ss += __shfl_xor(ss, 16);
            ss += __shfl_xor(ss, 32);
            if (t < 8) pv[t] = ss;
        } else if (t < 128) {
            int u = t - 64, j = u & 15, ch = u >> 4;
            float ss = 0.f;
            int c0 = ch * 32;
            for (int cc = c0; cc < c0 + 32; cc += 2) {
                unsigned hh = *(const unsigned*)&xch[j][cc];
                unsigned ll = *(const unsigned*)&xcl[j][cc];
                float v0 = bfpair((unsigned short)hh, (unsigned short)ll);
                float v1 = bfpair((unsigned short)(hh >> 16), (unsigned short)(ll >> 16));
                ss += vtl[cc] * v0 + vtl[cc + 1] * v1;
            }
            ss += __shfl_xor(ss, 16);
            ss += __shfl_xor(ss, 32);
            if (u < 16) tv[u] = ss + ctp[0];
        }
    }
    __syncthreads();
    // -------- phase 4: y (1024 units over 512 threads)
    #pragma unroll
    for (int u2 = 0; u2 < 2; u2++) {
        int u = t + u2 * 512;
        int j = u >> 6, c = u & 63;
        float ss = 0.f;
        #pragma unroll
        for (int w2 = 0; w2 < 8; w2++)
            ss += fmaxf(tv[j] + pv[w2], 0.f) * gx[c][w2];
        unsigned short h2, l2;
        splitbf(ss * 0.125f, h2, l2);
        ybh[j][c] = h2; ybl[j][c] = l2;
    }
    __syncthreads();
    // -------- phase 5: Wy MFMA (8 tiles over 8 waves)
    {
        int mt = w;
        short8 byh0 = *(const short8*)&ybh[mn][kq];
        short8 byh1 = *(const short8*)&ybh[mn][32 + kq];
        short8 byl0 = *(const short8*)&ybl[mn][kq];
        short8 byl1 = *(const short8*)&ybl[mn][32 + kq];
        const unsigned short* aph = nlWh + (size_t)(mt * 16 + mn) * 64 + kq;
        const unsigned short* apl = nlWl + (size_t)(mt * 16 + mn) * 64 + kq;
        f32x4 acc = {0.f, 0.f, 0.f, 0.f};
        acc = mfma_split(*(const short8*)aph, *(const short8*)apl, byh0, byl0, acc);
        acc = mfma_split(*(const short8*)(aph + 32), *(const short8*)(apl + 32), byh1, byl1, acc);
        #pragma unroll
        for (int r = 0; r < 4; r++) {
            int o = mt * 16 + qr + r;
            WYL(o, mn) = acc[r] + W_b[o];
        }
    }
    __syncthreads();
    // -------- phase 6a: stats reduction from WYL (LDS only, no stores yet)
    {
        int c = t & 127;
        float ss = 0.f, qq = 0.f;
        #pragma unroll
        for (int u2 = 0; u2 < 4; u2++) {
            int idx = t + u2 * 512;
            float v = WYL(c, idx >> 7);
            ss += v; qq += v * v;
        }
        redS[t] = ss; redQ[t] = qq;
    }
    __syncthreads();
    // -------- phase 6b: atomics + ALL global stores past the last barrier
    {
        float* so = wst + (b & (NREP - 1)) * 256;
        if (t < 128) {
            float s4 = redS[t] + redS[t + 128] + redS[t + 256] + redS[t + 384];
            float q4 = redQ[t] + redQ[t + 128] + redQ[t + 256] + redQ[t + 384];
            atomicAdd(&so[t], s4);
            atomicAdd(&so[128 + t], q4);
        }
        int c = t & 127;
        #pragma unroll
        for (int u2 = 0; u2 < 4; u2++) {
            int idx = t + u2 * 512;
            wydst[(size_t)b * 2048 + idx] = WYL(c, idx >> 7);
        }
        ((float4*)hdst)[(size_t)b * 512 + t] = hv;
    }
}

// ---------------------------------------------------------------- gconv out (128->3), fused nl_b
__global__ __launch_bounds__(256) void gconv_out_kernel(
        const float* __restrict__ h, const float* __restrict__ wy,
        const float* __restrict__ stats_in,
        const float* __restrict__ nlg, const float* __restrict__ nlb,
        const int* __restrict__ restored,
        const float* __restrict__ W,
        const float* __restrict__ bias, const float* __restrict__ off,
        const float* __restrict__ diag, float* __restrict__ out) {
    __shared__ float hs[16][132];
    __shared__ float gsv[16][132];
    __shared__ float offs[256];
    __shared__ float p0[48][4], p1[48][4];
    int b = blockIdx.x, t = threadIdx.x;
    offs[t] = off[t];
    float* hsf = &hs[0][0];
    {
        float ssum = 0.f;
        #pragma unroll
        for (int rr = 0; rr < NREP; rr++) ssum += stats_in[rr * 256 + t];
        hsf[t] = ssum;
    }
    __syncthreads();
    int c = t & 127;
    float mean, inv, bbv;
    {
        const float K = 1.f / 65536.f;
        mean = hsf[c] * K;
        float varv = hsf[128 + c] * K - mean * mean;
        inv = rsqrtf(varv + 1e-5f) * nlg[c];
        bbv = nlb[c];
    }
    __syncthreads();
    {
        for (int idx = t; idx < 2048; idx += 256) {
            int r = idx >> 7;
            float wval = wy[(size_t)b * 2048 + restored[r] * 128 + c];
            hs[r][c] = (wval - mean) * inv + bbv + h[(size_t)b * 2048 + idx];
        }
    }
    __syncthreads();
    for (int idx = t; idx < 2048; idx += 256) {
        int i = idx >> 7, f = idx & 127;
        float g = 0.f;
        #pragma unroll
        for (int j = 0; j < 16; j++) g += offs[i * 16 + j] * hs[j][f];
        gsv[i][f] = g;
    }
    __syncthreads();
    if (t < 192) {
        int oid = t >> 2, chunk = t & 3;
        int i = oid / 3, o = oid % 3;
        float a0 = 0.f, a1 = 0.f;
        int f0 = chunk * 32;
        for (int f = f0; f < f0 + 32; f++) {
            a0 += hs[i][f] * W[f * 3 + o];
            a1 += gsv[i][f] * W[384 + f * 3 + o];
        }
        p0[oid][chunk] = a0; p1[oid][chunk] = a1;
    }
    __syncthreads();
    if (t < 48) {
        int i = t / 3, o = t % 3;
        float a0 = p0[t][0] + p0[t][1] + p0[t][2] + p0[t][3];
        float a1 = p1[t][0] + p1[t][1] + p1[t][2] + p1[t][3];
        out[(size_t)b * 48 + t] = diag[i] * a0 + a1 + bias[o];
    }
}

// ================================================================ launch
extern "C" void kernel_launch(void* const* d_in, const int* in_sizes, int n_in,
                              void* d_out, int out_size, void* d_ws, size_t ws_size,
                              hipStream_t stream) {
    (void)n_in; (void)out_size; (void)ws_size;
    const float* x        = (const float*)d_in[0];
    const float* gc_in_W  = (const float*)d_in[1];
    const float* gc_in_e  = (const float*)d_in[2];
    const float* gc_in_b  = (const float*)d_in[3];
    const float* bn_in_g  = (const float*)d_in[4];
    const float* bn_in_b  = (const float*)d_in[5];
    const float* W_res    = (const float*)d_in[6];
    const float* e_res    = (const float*)d_in[7];
    const float* b_res    = (const float*)d_in[8];
    const float* bng_res  = (const float*)d_in[9];
    const float* bnb_res  = (const float*)d_in[10];
    const float* nl_g_w   = (const float*)d_in[11];
    const float* nl_g_b   = (const float*)d_in[12];
    const float* nl_t_w   = (const float*)d_in[13];
    const float* nl_t_b   = (const float*)d_in[14];
    const float* nl_p_w   = (const float*)d_in[15];
    const float* nl_p_b   = (const float*)d_in[16];
    const float* nl_cp_w  = (const float*)d_in[17];
    const float* nl_W_w   = (const float*)d_in[18];
    const float* nl_W_b   = (const float*)d_in[19];
    const float* nl_bn_g  = (const float*)d_in[20];
    const float* nl_bn_b  = (const float*)d_in[21];
    const float* gc_out_W = (const float*)d_in[22];
    const float* gc_out_e = (const float*)d_in[23];
    const float* gc_out_b = (const float*)d_in[24];
    const int*   mask_rows = (const int*)d_in[25];
    const int*   mask_cols = (const int*)d_in[26];
    const int*   restored  = (const int*)d_in[28];
    int nnz = in_sizes[2];

    float* ws       = (float*)d_ws;
    float* off_all  = ws;                  // 0..2560
    float* diag_all = ws + 2560;           // ..2720
    float* stats    = ws + 2720;           // 14 x 4096 -> ..60064
    float* vt       = ws + 63664;          // 5 x 128
    float* ct       = ws + 64304;          // 5
    unsigned short* Wbh  = (unsigned short*)(ws + 65536);
    unsigned short* Wbl  = Wbh + WB_N;
    unsigned short* nlwh = Wbl + WB_N;
    unsigned short* nlwl = nlwh + NLW_N;
    unsigned short* nlWh = nlwl + NLW_N;
    unsigned short* nlWl = nlWh + NLWW_N;  // ends at float 491520
    float* Z = ws + 491520;
    float* T = Z + ELEMS;

    // fused head: prep_w + adj + prep_vt + stats-zero in ONE dispatch
    prep_all_kernel<<<PREPW_BLKS + 15 + 14, 256, 0, stream>>>(
        W_res, nl_g_w, nl_t_w, nl_p_w, nl_W_w,
        Wbh, Wbl, nlwh, nlwl, nlWh, nlWl,
        gc_in_e, e_res, gc_out_e, mask_rows, mask_cols, nnz,
        off_all, diag_all,
        nl_t_b, nl_cp_w, vt, ct, stats);

    // t0 -> T, slot 0
    gconv_in_kernel<<<B, 256, 0, stream>>>(x, gc_in_W, gc_in_b, off_all, diag_all,
                                           T, stats);
    // nonlocal 0: h0 -> Z; wy -> T, slot 1
    nl_a_kernel<<<B, 512, 0, stream>>>(T, stats, bn_in_g, bn_in_b, nullptr,
                                       nlwh, nlwl, nl_g_b, nl_p_b, nl_cp_w,
                                       vt, ct, nlWh, nlWl, nl_W_b, restored,
                                       Z, T, stats + SLOT);

    int sl = 1;
    for (int i = 0; i < NLAYERS; i++) {
        int l0 = 2 * i, l1 = 2 * i + 1, li = i + 1;
        // gconv1 + fused nl_b: z -> Z; t1 -> T, slot sl+1
        gconv_mfma_kernel<<<2048, 256, 0, stream>>>(
            Z, T, stats + (size_t)sl * SLOT,
            nl_bn_g + i * 128, nl_bn_b + i * 128, restored, Z,
            Wbh + (size_t)l0 * 32768, Wbl + (size_t)l0 * 32768, b_res + l0 * 128,
            off_all + (1 + l0) * 256, diag_all + (1 + l0) * 16, T,
            stats + (size_t)(sl + 1) * SLOT);
        // gconv2: t2 -> T, slot sl+2
        gconv_mfma_kernel<<<2048, 256, 0, stream>>>(
            T, nullptr, stats + (size_t)(sl + 1) * SLOT,
            bng_res + l0 * 128, bnb_res + l0 * 128, nullptr, nullptr,
            Wbh + (size_t)l1 * 32768, Wbl + (size_t)l1 * 32768, b_res + l1 * 128,
            off_all + (1 + l1) * 256, diag_all + (1 + l1) * 16, T,
            stats + (size_t)(sl + 2) * SLOT);
        // nl_a: h -> Z; wy -> T, slot sl+3
        nl_a_kernel<<<B, 512, 0, stream>>>(
            T, stats + (size_t)(sl + 2) * SLOT,
            bng_res + l1 * 128, bnb_res + l1 * 128, Z,
            nlwh + li * 24576, nlwl + li * 24576,
            nl_g_b + li * 64, nl_p_b + li * 64, nl_cp_w + li * 128,
            vt + li * 128, ct + li, nlWh + li * 8192, nlWl + li * 8192,
            nl_W_b + li * 128, restored, Z, T,
            stats + (size_t)(sl + 3) * SLOT);
        sl += 3;
    }
    gconv_out_kernel<<<B, 256, 0, stream>>>(Z, T, stats + (size_t)sl * SLOT,
                                            nl_bn_g + NLAYERS * 128, nl_bn_b + NLAYERS * 128,
                                            restored, gc_out_W, gc_out_b,
                                            off_all + 9 * 256, diag_all + 9 * 16,
                                            (float*)d_out);
}

// Round 11
// 872.656 us; speedup vs baseline: 2.6261x; 1.0012x over previous
//
#include <hip/hip_runtime.h>

#define B 4096
#define J 16
#define HID 128
#define INTER 64
#define NLAYERS 4
#define NEGV -9000000000000000.0f
#define ELEMS ((size_t)B*16*128)
#define NREP 16
#define SLOT 4096

typedef __attribute__((ext_vector_type(8))) short short8;
typedef __attribute__((ext_vector_type(4))) float f32x4;

static __device__ __forceinline__ unsigned short f2bf(float x) {
    unsigned u = __float_as_uint(x);
    unsigned r = u + 0x7fffu + ((u >> 16) & 1u);
    return (unsigned short)(r >> 16);
}
static __device__ __forceinline__ void splitbf(float x, unsigned short& h, unsigned short& l) {
    h = f2bf(x);
    float hf = __uint_as_float((unsigned)h << 16);
    l = f2bf(x - hf);
}
static __device__ __forceinline__ void splitbf4(float4 v, uint2& hh, uint2& ll) {
    unsigned short h0,l0,h1,l1,h2,l2,h3,l3;
    splitbf(v.x,h0,l0); splitbf(v.y,h1,l1); splitbf(v.z,h2,l2); splitbf(v.w,h3,l3);
    hh = make_uint2((unsigned)h0 | ((unsigned)h1<<16), (unsigned)h2 | ((unsigned)h3<<16));
    ll = make_uint2((unsigned)l0 | ((unsigned)l1<<16), (unsigned)l2 | ((unsigned)l3<<16));
}
static __device__ __forceinline__ f32x4 mfma16(short8 a, short8 b, f32x4 c) {
    return __builtin_amdgcn_mfma_f32_16x16x32_bf16(a, b, c, 0, 0, 0);
}
static __device__ __forceinline__ f32x4 mfma_split(short8 ah, short8 al,
                                                   short8 bh, short8 bl, f32x4 acc) {
    acc = mfma16(ah, bh, acc);
    acc = mfma16(ah, bl, acc);
    acc = mfma16(al, bh, acc);
    return acc;
}
static __device__ __forceinline__ float bfpair(unsigned short h, unsigned short l) {
    return __uint_as_float((unsigned)h << 16) + __uint_as_float((unsigned)l << 16);
}

// ---------------------------------------------------------------- fused prep
#define WB_N   262144
#define NLW_N  122880
#define NLWW_N 40960
#define PREPW_BLKS 1664   // (WB_N+NLW_N+NLWW_N)/256 exactly
__global__ __launch_bounds__(256) void prep_all_kernel(
        const float* __restrict__ W_res,
        const float* __restrict__ g_w, const float* __restrict__ t_w,
        const float* __restrict__ p_w, const float* __restrict__ W_w,
        unsigned short* __restrict__ Wbh, unsigned short* __restrict__ Wbl,
        unsigned short* __restrict__ nlwh, unsigned short* __restrict__ nlwl,
        unsigned short* __restrict__ nlWh, unsigned short* __restrict__ nlWl,
        const float* __restrict__ e_in, const float* __restrict__ e_res,
        const float* __restrict__ e_out,
        const int* __restrict__ rows, const int* __restrict__ cols, int nnz,
        float* __restrict__ off_all, float* __restrict__ diag_all,
        const float* __restrict__ t_b, const float* __restrict__ cp_w,
        float* __restrict__ vt, float* __restrict__ ct,
        float* __restrict__ stats) {
    int blk = blockIdx.x, t = threadIdx.x;
    if (blk < PREPW_BLKS) {
        int i = blk * 256 + t;
        unsigned short h, l;
        if (i < WB_N) {
            int lay = i >> 15, rem = i & 32767, n = rem >> 8, k = rem & 255;
            int d = k >> 7, f = k & 127;
            splitbf(W_res[(((lay << 1) | d) * 128 + f) * 128 + n], h, l);
            Wbh[i] = h; Wbl[i] = l;
        } else if (i < WB_N + NLW_N) {
            int j = i - WB_N;
            int lay = j / 24576, r2 = j % 24576;
            int conv = r2 >> 13, oc = r2 & 8191;
            const float* src = conv == 0 ? g_w : conv == 1 ? t_w : p_w;
            splitbf(src[lay * 8192 + oc], h, l);
            nlwh[j] = h; nlwl[j] = l;
        } else {
            int j = i - WB_N - NLW_N;
            splitbf(W_w[j], h, l);
            nlWh[j] = h; nlWl[j] = l;
        }
    } else if (blk < PREPW_BLKS + 10) {
        if (t < 16) {
            int m = blk - PREPW_BLKS;
            int i = t;
            const float* e = (m == 0) ? e_in : (m <= 8) ? e_res + (size_t)(m - 1) * nnz : e_out;
            float l[16];
            for (int j = 0; j < 16; j++) l[j] = NEGV;
            for (int k = 0; k < nnz; k++)
                if (rows[k] == i) l[cols[k]] = e[k];
            float mx = l[0];
            for (int j = 1; j < 16; j++) mx = fmaxf(mx, l[j]);
            float ex[16], s = 0.f;
            for (int j = 0; j < 16; j++) { ex[j] = expf(l[j] - mx); s += ex[j]; }
            float inv = 1.f / s;
            for (int j = 0; j < 16; j++) {
                float a = ex[j] * inv;
                if (j == i) { diag_all[m * 16 + i] = a; a = 0.f; }
                off_all[m * 256 + i * 16 + j] = a;
            }
        }
    } else if (blk < PREPW_BLKS + 15) {
        if (t < 128) {
            int l = blk - PREPW_BLKS - 10, c = t;
            float s = 0.f;
            for (int c2 = 0; c2 < 64; c2++)
                s += cp_w[l * 128 + c2] * t_w[(l * 64 + c2) * 128 + c];
            vt[l * 128 + c] = s;
            if (c == 0) {
                float s2 = 0.f;
                for (int c2 = 0; c2 < 64; c2++) s2 += cp_w[l * 128 + c2] * t_b[l * 64 + c2];
                ct[l] = s2;
            }
        }
    } else {
        int sl_ = blk - PREPW_BLKS - 15;   // 0..13
        float* dst = stats + (size_t)sl_ * SLOT;
        #pragma unroll
        for (int u = 0; u < 16; u++) dst[t + u * 256] = 0.f;
    }
}

// ---------------------------------------------------------------- gconv in (F=2)
__global__ __launch_bounds__(256) void gconv_in_kernel(
        const float* __restrict__ x, const float* __restrict__ W,
        const float* __restrict__ bias, const float* __restrict__ off,
        const float* __restrict__ diag, float* __restrict__ out,
        float* __restrict__ stats_out) {
    __shared__ float xs[16][2];
    __shared__ float gs[16][2];
    __shared__ float red[512];
    int b = blockIdx.x, t = threadIdx.x;
    if (t < 32) xs[t >> 1][t & 1] = x[b * 32 + t];
    __syncthreads();
    if (t < 32) {
        int i = t >> 1, f = t & 1;
        float g = 0.f;
        #pragma unroll
        for (int j = 0; j < 16; j++) g += off[i * 16 + j] * xs[j][f];
        gs[i][f] = g;
    }
    __syncthreads();
    int o = t & 127;
    float w00 = W[o], w01 = W[128 + o], w10 = W[256 + o], w11 = W[384 + o], bo = bias[o];
    float s = 0.f, q = 0.f;
    float vals[8];
    #pragma unroll
    for (int u = 0; u < 8; u++) {
        int idx = t + u * 256;
        int i = idx >> 7;
        float v = diag[i] * (xs[i][0] * w00 + xs[i][1] * w01)
                + gs[i][0] * w10 + gs[i][1] * w11 + bo;
        vals[u] = v;
        s += v; q += v * v;
    }
    red[t] = s; red[256 + t] = q;
    __syncthreads();
    float* so = stats_out + (b & (NREP - 1)) * 256;
    if (t < 128) {
        atomicAdd(&so[t], red[t] + red[t + 128]);
        atomicAdd(&so[128 + t], red[256 + t] + red[256 + t + 128]);
    }
    #pragma unroll
    for (int u = 0; u < 8; u++)
        out[(size_t)b * 2048 + t + u * 256] = vals[u];
}

// ---------------------------------------------------------------- gconv 128->128
// R6-verified version (58 us/dispatch): zdst stored in phase 0, inline stats
// atomics. (R9's deferred-zdst variant failed to bench 4x — reverted.)
__global__ __launch_bounds__(256) void gconv_mfma_kernel(
        const float* src, const float* wy,
        const float* __restrict__ stats_in,
        const float* __restrict__ bn_g, const float* __restrict__ bn_b,
        const int* __restrict__ restored, float* zdst,
        const unsigned short* __restrict__ Wbh,
        const unsigned short* __restrict__ Wbl,
        const float* __restrict__ bias,
        const float* __restrict__ off, const float* __restrict__ diag,
        float* dst, float* __restrict__ stats_out) {
    __shared__ float hraw[16][132];
    __shared__ __align__(16) unsigned short ksh[16][264];
    __shared__ __align__(16) unsigned short ksl[16][264];
    __shared__ float offs[256];
    __shared__ float diags[16];
    int t = threadIdx.x;
    offs[t] = off[t];
    if (t < 16) diags[t] = diag[t];
    float* hrawf = &hraw[0][0];
    {
        float ssum = 0.f;
        #pragma unroll
        for (int rr = 0; rr < NREP; rr++) ssum += stats_in[rr * 256 + t];
        hrawf[t] = ssum;
    }
    int c4 = (4 * t) & 127;
    int r0 = t >> 5;
    int ro0 = 0, ro1 = 0;
    if (wy) { ro0 = restored[r0]; ro1 = restored[r0 + 8]; }
    int b0 = blockIdx.x;
    const float4* src4 = (const float4*)src;
    const float4* wy4  = (const float4*)wy;
    float4 sv0 = src4[(size_t)b0 * 512 + t];
    float4 sv1 = src4[(size_t)b0 * 512 + 256 + t];
    float4 wv0 = make_float4(0,0,0,0), wv1 = make_float4(0,0,0,0);
    if (wy) {
        wv0 = wy4[(size_t)b0 * 512 + ro0 * 32 + (c4 >> 2)];
        wv1 = wy4[(size_t)b0 * 512 + ro1 * 32 + (c4 >> 2)];
    }
    __syncthreads();
    float4 m4, sc4, bb4;
    {
        const float K = 1.f / 65536.f;
        float4 g4 = *(const float4*)&bn_g[c4];
        bb4 = *(const float4*)&bn_b[c4];
        float m0 = hrawf[c4]     * K, m1 = hrawf[c4 + 1] * K;
        float m2 = hrawf[c4 + 2] * K, m3 = hrawf[c4 + 3] * K;
        float i0 = rsqrtf(hrawf[128 + c4]     * K - m0 * m0 + 1e-5f);
        float i1 = rsqrtf(hrawf[128 + c4 + 1] * K - m1 * m1 + 1e-5f);
        float i2 = rsqrtf(hrawf[128 + c4 + 2] * K - m2 * m2 + 1e-5f);
        float i3 = rsqrtf(hrawf[128 + c4 + 3] * K - m3 * m3 + 1e-5f);
        m4 = make_float4(m0, m1, m2, m3);
        sc4 = make_float4(i0 * g4.x, i1 * g4.y, i2 * g4.z, i3 * g4.w);
    }
    __syncthreads();
    int wv_ = t >> 6, lane = t & 63;
    int mn = lane & 15, kq = (lane >> 4) << 3, qr = (lane >> 4) << 2;

    for (int s = 0; s < 2; s++) {
        int bb_ = blockIdx.x + s * 2048;
        {
            float4 v = sv0;
            if (wy) {
                v.x += (wv0.x - m4.x) * sc4.x + bb4.x;
                v.y += (wv0.y - m4.y) * sc4.y + bb4.y;
                v.z += (wv0.z - m4.z) * sc4.z + bb4.z;
                v.w += (wv0.w - m4.w) * sc4.w + bb4.w;
                ((float4*)zdst)[(size_t)bb_ * 512 + t] = v;
            } else {
                v.x = fmaxf((v.x - m4.x) * sc4.x + bb4.x, 0.f);
                v.y = fmaxf((v.y - m4.y) * sc4.y + bb4.y, 0.f);
                v.z = fmaxf((v.z - m4.z) * sc4.z + bb4.z, 0.f);
                v.w = fmaxf((v.w - m4.w) * sc4.w + bb4.w, 0.f);
            }
            *(float4*)&hraw[r0][c4] = v;
            v = sv1;
            if (wy) {
                v.x += (wv1.x - m4.x) * sc4.x + bb4.x;
                v.y += (wv1.y - m4.y) * sc4.y + bb4.y;
                v.z += (wv1.z - m4.z) * sc4.z + bb4.z;
                v.w += (wv1.w - m4.w) * sc4.w + bb4.w;
                ((float4*)zdst)[(size_t)bb_ * 512 + 256 + t] = v;
            } else {
                v.x = fmaxf((v.x - m4.x) * sc4.x + bb4.x, 0.f);
                v.y = fmaxf((v.y - m4.y) * sc4.y + bb4.y, 0.f);
                v.z = fmaxf((v.z - m4.z) * sc4.z + bb4.z, 0.f);
                v.w = fmaxf((v.w - m4.w) * sc4.w + bb4.w, 0.f);
            }
            *(float4*)&hraw[r0 + 8][c4] = v;
        }
        if (s == 0) {
            int b1 = blockIdx.x + 2048;
            sv0 = src4[(size_t)b1 * 512 + t];
            sv1 = src4[(size_t)b1 * 512 + 256 + t];
            if (wy) {
                wv0 = wy4[(size_t)b1 * 512 + ro0 * 32 + (c4 >> 2)];
                wv1 = wy4[(size_t)b1 * 512 + ro1 * 32 + (c4 >> 2)];
            }
        }
        __syncthreads();
        for (int u = t; u < 512; u += 256) {
            int i = u >> 5, f4 = (u & 31) << 2;
            float4 hv = *(const float4*)&hraw[i][f4];
            float4 g = make_float4(0.f, 0.f, 0.f, 0.f);
            #pragma unroll
            for (int j = 0; j < 16; j++) {
                float w = offs[i * 16 + j];
                float4 hj = *(const float4*)&hraw[j][f4];
                g.x += w * hj.x; g.y += w * hj.y; g.z += w * hj.z; g.w += w * hj.w;
            }
            float d = diags[i];
            uint2 hh, ll;
            splitbf4(make_float4(d * hv.x, d * hv.y, d * hv.z, d * hv.w), hh, ll);
            *(uint2*)&ksh[i][f4] = hh;
            *(uint2*)&ksl[i][f4] = ll;
            splitbf4(g, hh, ll);
            *(uint2*)&ksh[i][128 + f4] = hh;
            *(uint2*)&ksl[i][128 + f4] = ll;
        }
        __syncthreads();
        int n0 = wv_ << 5;
        f32x4 acc0 = {0.f, 0.f, 0.f, 0.f}, acc1 = {0.f, 0.f, 0.f, 0.f};
        const unsigned short* wh0 = Wbh + (size_t)(n0 + mn) * 256 + kq;
        const unsigned short* wl0 = Wbl + (size_t)(n0 + mn) * 256 + kq;
        #pragma unroll
        for (int k = 0; k < 8; k++) {
            int k0 = k << 5;
            short8 ah = *(const short8*)&ksh[mn][k0 + kq];
            short8 al = *(const short8*)&ksl[mn][k0 + kq];
            acc0 = mfma_split(ah, al, *(const short8*)(wh0 + k0), *(const short8*)(wl0 + k0), acc0);
            acc1 = mfma_split(ah, al, *(const short8*)(wh0 + 4096 + k0), *(const short8*)(wl0 + 4096 + k0), acc1);
        }
        float bias0 = bias[n0 + mn], bias1 = bias[n0 + 16 + mn];
        float s0 = 0.f, q0 = 0.f, s1 = 0.f, q1 = 0.f;
        #pragma unroll
        for (int r = 0; r < 4; r++) {
            int row = qr + r;
            float v0 = acc0[r] + bias0;
            float v1 = acc1[r] + bias1;
            dst[(size_t)bb_ * 2048 + row * 128 + n0 + mn] = v0;
            dst[(size_t)bb_ * 2048 + row * 128 + n0 + 16 + mn] = v1;
            s0 += v0; q0 += v0 * v0; s1 += v1; q1 += v1 * v1;
        }
        s0 += __shfl_xor(s0, 16); s0 += __shfl_xor(s0, 32);
        q0 += __shfl_xor(q0, 16); q0 += __shfl_xor(q0, 32);
        s1 += __shfl_xor(s1, 16); s1 += __shfl_xor(s1, 32);
        q1 += __shfl_xor(q1, 16); q1 += __shfl_xor(q1, 32);
        float* so = stats_out + (bb_ & (NREP - 1)) * 256;
        if (lane < 16) {
            atomicAdd(&so[n0 + mn], s0);
            atomicAdd(&so[128 + n0 + mn], q0);
            atomicAdd(&so[n0 + 16 + mn], s1);
            atomicAdd(&so[128 + n0 + 16 + mn], q1);
        }
        if (s == 0) __syncthreads();
    }
}

// ---------------------------------------------------------------- nonlocal A
// 512 threads, ONE sample (grid 4096). R8-verified (66 us): single prologue
// barrier, h held in 4 VGPRs stored at kernel end, all global stores past
// the last barrier.
#define CG(conv, o, j) cgbuf[((conv) * 64 + (o)) * 17 + (j)]
#define WYL(o, j)      cgbuf[(o) * 17 + (j)]
__global__ __launch_bounds__(512, 8) void nl_a_kernel(
        const float* tsrc, const float* __restrict__ stats_in,
        const float* __restrict__ bn_g, const float* __restrict__ bn_b,
        const float* res,
        const unsigned short* __restrict__ nlwh,
        const unsigned short* __restrict__ nlwl,
        const float* __restrict__ g_b, const float* __restrict__ p_b,
        const float* __restrict__ cpw,
        const float* __restrict__ vt, const float* __restrict__ ctp,
        const unsigned short* __restrict__ nlWh,
        const unsigned short* __restrict__ nlWl,
        const float* __restrict__ W_b,
        const int* __restrict__ restored,
        float* hdst, float* wydst, float* __restrict__ wst) {
    __shared__ __align__(16) unsigned short xch[16][136];
    __shared__ __align__(16) unsigned short xcl[16][136];
    __shared__ float cgbuf[2176];
    __shared__ float gx[64][9];
    __shared__ float tv[16], pv[8];
    __shared__ float vtl[128];
    __shared__ __align__(16) float bnm[128], bnsc[128], bnbb[128];
    __shared__ __align__(16) unsigned short ybh[16][72];
    __shared__ __align__(16) unsigned short ybl[16][72];
    __shared__ float redS[512], redQ[512];
    int t = threadIdx.x, b = blockIdx.x;
    const float4* tsrc4 = (const float4*)tsrc;
    float4 sv = tsrc4[(size_t)b * 512 + t];
    float4 rv = make_float4(0.f, 0.f, 0.f, 0.f);
    if (res) rv = ((const float4*)res)[(size_t)b * 512 + t];
    if (t < 128) {
        float s_ = 0.f, q_ = 0.f;
        #pragma unroll
        for (int rr = 0; rr < NREP; rr++) {
            s_ += stats_in[rr * 256 + t];
            q_ += stats_in[rr * 256 + 128 + t];
        }
        const float K = 1.f / 65536.f;
        float mean = s_ * K;
        float varv = q_ * K - mean * mean;
        bnm[t] = mean;
        bnsc[t] = rsqrtf(varv + 1e-5f) * bn_g[t];
        bnbb[t] = bn_b[t];
    } else if (t < 256) {
        vtl[t - 128] = vt[t - 128];
    }
    int c4 = (4 * t) & 127;
    int r0 = t >> 5;
    int rg = restored[r0];
    __syncthreads();                 // single prologue barrier
    int w = t >> 6, lane = t & 63;
    int mn = lane & 15, kq = (lane >> 4) << 3, qr = (lane >> 4) << 2;
    float4 hv;                       // held until kernel end (4 VGPRs only)
    {
        float4 m4 = *(const float4*)&bnm[c4];
        float4 sc4 = *(const float4*)&bnsc[c4];
        float4 bb4 = *(const float4*)&bnbb[c4];
        hv.x = fmaxf((sv.x - m4.x) * sc4.x + bb4.x, 0.f) + rv.x;
        hv.y = fmaxf((sv.y - m4.y) * sc4.y + bb4.y, 0.f) + rv.y;
        hv.z = fmaxf((sv.z - m4.z) * sc4.z + bb4.z, 0.f) + rv.z;
        hv.w = fmaxf((sv.w - m4.w) * sc4.w + bb4.w, 0.f) + rv.w;
        uint2 hh, ll;
        splitbf4(hv, hh, ll);
        *(uint2*)&xch[rg][c4] = hh;
        *(uint2*)&xcl[rg][c4] = ll;
    }
    __syncthreads();
    {
        int conv = w >> 2;          // 0=g, 1=p
        int mt = w & 3;
        int wbase = (conv == 0) ? 0 : 128;
        const unsigned short* aph = nlwh + (size_t)(wbase + mt * 16 + mn) * 128 + kq;
        const unsigned short* apl = nlwl + (size_t)(wbase + mt * 16 + mn) * 128 + kq;
        f32x4 acc = {0.f, 0.f, 0.f, 0.f};
        #pragma unroll
        for (int k = 0; k < 4; k++) {
            short8 bh = *(const short8*)&xch[mn][k * 32 + kq];
            short8 bl = *(const short8*)&xcl[mn][k * 32 + kq];
            acc = mfma_split(*(const short8*)(aph + k * 32), *(const short8*)(apl + k * 32),
                             bh, bl, acc);
        }
        const float* biasp = (conv == 0) ? g_b : p_b;
        #pragma unroll
        for (int r = 0; r < 4; r++) {
            int o = mt * 16 + qr + r;
            CG(conv, o, mn) = acc[r] + biasp[o];
        }
    }
    __syncthreads();
    {
        int c = t >> 3, w2 = t & 7;
        gx[c][w2] = fmaxf(CG(0, c, 2 * w2), CG(0, c, 2 * w2 + 1));
        if (t < 64) {
            int ch = t >> 3;
            float ss = 0.f;
            for (int cc = ch * 8; cc < ch * 8 + 8; cc++)
                ss += fmaxf(CG(1, cc, 2 * w2), CG(1, cc, 2 * w2 + 1)) * cpw[64 + cc];
            ss += __shfl_xor(ss, 8);
            ss += __shfl_xor(ss, 16);
            ss += __shfl_xor(ss, 32);
            if (t < 8) pv[t] = ss;
        } else if (t < 128) {
            int u = t - 64, j = u & 15, ch = u >> 4;
            float ss = 0.f;
            int c0 = ch * 32;
            for (int cc = c0; cc < c0 + 32; cc += 2) {
                unsigned hh = *(const unsigned*)&xch[j][cc];
                unsigned ll = *(const unsigned*)&xcl[j][cc];
                float v0 = bfpair((unsigned short)hh, (unsigned short)ll);
                float v1 = bfpair((unsigned short)(hh >> 16), (unsigned short)(ll >> 16));
                ss += vtl[cc] * v0 + vtl[cc + 1] * v1;
            }
            ss += __shfl_xor(ss, 16);
            ss += __shfl_xor(ss, 32);
            if (u < 16) tv[u] = ss + ctp[0];
        }
    }
    __syncthreads();
    #pragma unroll
    for (int u2 = 0; u2 < 2; u2++) {
        int u = t + u2 * 512;
        int j = u >> 6, c = u & 63;
        float ss = 0.f;
        #pragma unroll
        for (int w2 = 0; w2 < 8; w2++)
            ss += fmaxf(tv[j] + pv[w2], 0.f) * gx[c][w2];
        unsigned short h2, l2;
        splitbf(ss * 0.125f, h2, l2);
        ybh[j][c] = h2; ybl[j][c] = l2;
    }
    __syncthreads();
    {
        int mt = w;
        short8 byh0 = *(const short8*)&ybh[mn][kq];
        short8 byh1 = *(const short8*)&ybh[mn][32 + kq];
        short8 byl0 = *(const short8*)&ybl[mn][kq];
        short8 byl1 = *(const short8*)&ybl[mn][32 + kq];
        const unsigned short* aph = nlWh + (size_t)(mt * 16 + mn) * 64 + kq;
        const unsigned short* apl = nlWl + (size_t)(mt * 16 + mn) * 64 + kq;
        f32x4 acc = {0.f, 0.f, 0.f, 0.f};
        acc = mfma_split(*(const short8*)aph, *(const short8*)apl, byh0, byl0, acc);
        acc = mfma_split(*(const short8*)(aph + 32), *(const short8*)(apl + 32), byh1, byl1, acc);
        #pragma unroll
        for (int r = 0; r < 4; r++) {
            int o = mt * 16 + qr + r;
            WYL(o, mn) = acc[r] + W_b[o];
        }
    }
    __syncthreads();
    {
        int c = t & 127;
        float ss = 0.f, qq = 0.f;
        #pragma unroll
        for (int u2 = 0; u2 < 4; u2++) {
            int idx = t + u2 * 512;
            float v = WYL(c, idx >> 7);
            ss += v; qq += v * v;
        }
        redS[t] = ss; redQ[t] = qq;
    }
    __syncthreads();
    {
        float* so = wst + (b & (NREP - 1)) * 256;
        if (t < 128) {
            float s4 = redS[t] + redS[t + 128] + redS[t + 256] + redS[t + 384];
            float q4 = redQ[t] + redQ[t + 128] + redQ[t + 256] + redQ[t + 384];
            atomicAdd(&so[t], s4);
            atomicAdd(&so[128 + t], q4);
        }
        int c = t & 127;
        #pragma unroll
        for (int u2 = 0; u2 < 4; u2++) {
            int idx = t + u2 * 512;
            wydst[(size_t)b * 2048 + idx] = WYL(c, idx >> 7);
        }
        ((float4*)hdst)[(size_t)b * 512 + t] = hv;
    }
}

// ---------------------------------------------------------------- gconv out (128->3), fused nl_b
__global__ __launch_bounds__(256) void gconv_out_kernel(
        const float* __restrict__ h, const float* __restrict__ wy,
        const float* __restrict__ stats_in,
        const float* __restrict__ nlg, const float* __restrict__ nlb,
        const int* __restrict__ restored,
        const float* __restrict__ W,
        const float* __restrict__ bias, const float* __restrict__ off,
        const float* __restrict__ diag, float* __restrict__ out) {
    __shared__ float hs[16][132];
    __shared__ float gsv[16][132];
    __shared__ float offs[256];
    __shared__ float p0[48][4], p1[48][4];
    int b = blockIdx.x, t = threadIdx.x;
    offs[t] = off[t];
    float* hsf = &hs[0][0];
    {
        float ssum = 0.f;
        #pragma unroll
        for (int rr = 0; rr < NREP; rr++) ssum += stats_in[rr * 256 + t];
        hsf[t] = ssum;
    }
    __syncthreads();
    int c = t & 127;
    float mean, inv, bbv;
    {
        const float K = 1.f / 65536.f;
        mean = hsf[c] * K;
        float varv = hsf[128 + c] * K - mean * mean;
        inv = rsqrtf(varv + 1e-5f) * nlg[c];
        bbv = nlb[c];
    }
    __syncthreads();
    {
        for (int idx = t; idx < 2048; idx += 256) {
            int r = idx >> 7;
            float wval = wy[(size_t)b * 2048 + restored[r] * 128 + c];
            hs[r][c] = (wval - mean) * inv + bbv + h[(size_t)b * 2048 + idx];
        }
    }
    __syncthreads();
    for (int idx = t; idx < 2048; idx += 256) {
        int i = idx >> 7, f = idx & 127;
        float g = 0.f;
        #pragma unroll
        for (int j = 0; j < 16; j++) g += offs[i * 16 + j] * hs[j][f];
        gsv[i][f] = g;
    }
    __syncthreads();
    if (t < 192) {
        int oid = t >> 2, chunk = t & 3;
        int i = oid / 3, o = oid % 3;
        float a0 = 0.f, a1 = 0.f;
        int f0 = chunk * 32;
        for (int f = f0; f < f0 + 32; f++) {
            a0 += hs[i][f] * W[f * 3 + o];
            a1 += gsv[i][f] * W[384 + f * 3 + o];
        }
        p0[oid][chunk] = a0; p1[oid][chunk] = a1;
    }
    __syncthreads();
    if (t < 48) {
        int i = t / 3, o = t % 3;
        float a0 = p0[t][0] + p0[t][1] + p0[t][2] + p0[t][3];
        float a1 = p1[t][0] + p1[t][1] + p1[t][2] + p1[t][3];
        out[(size_t)b * 48 + t] = diag[i] * a0 + a1 + bias[o];
    }
}

// ================================================================ launch
extern "C" void kernel_launch(void* const* d_in, const int* in_sizes, int n_in,
                              void* d_out, int out_size, void* d_ws, size_t ws_size,
                              hipStream_t stream) {
    (void)n_in; (void)out_size; (void)ws_size;
    const float* x        = (const float*)d_in[0];
    const float* gc_in_W  = (const float*)d_in[1];
    const float* gc_in_e  = (const float*)d_in[2];
    const float* gc_in_b  = (const float*)d_in[3];
    const float* bn_in_g  = (const float*)d_in[4];
    const float* bn_in_b  = (const float*)d_in[5];
    const float* W_res    = (const float*)d_in[6];
    const float* e_res    = (const float*)d_in[7];
    const float* b_res    = (const float*)d_in[8];
    const float* bng_res  = (const float*)d_in[9];
    const float* bnb_res  = (const float*)d_in[10];
    const float* nl_g_w   = (const float*)d_in[11];
    const float* nl_g_b   = (const float*)d_in[12];
    const float* nl_t_w   = (const float*)d_in[13];
    const float* nl_t_b   = (const float*)d_in[14];
    const float* nl_p_w   = (const float*)d_in[15];
    const float* nl_p_b   = (const float*)d_in[16];
    const float* nl_cp_w  = (const float*)d_in[17];
    const float* nl_W_w   = (const float*)d_in[18];
    const float* nl_W_b   = (const float*)d_in[19];
    const float* nl_bn_g  = (const float*)d_in[20];
    const float* nl_bn_b  = (const float*)d_in[21];
    const float* gc_out_W = (const float*)d_in[22];
    const float* gc_out_e = (const float*)d_in[23];
    const float* gc_out_b = (const float*)d_in[24];
    const int*   mask_rows = (const int*)d_in[25];
    const int*   mask_cols = (const int*)d_in[26];
    const int*   restored  = (const int*)d_in[28];
    int nnz = in_sizes[2];

    float* ws       = (float*)d_ws;
    float* off_all  = ws;                  // 0..2560
    float* diag_all = ws + 2560;           // ..2720
    float* stats    = ws + 2720;           // 14 x 4096 -> ..60064
    float* vt       = ws + 63664;          // 5 x 128
    float* ct       = ws + 64304;          // 5
    unsigned short* Wbh  = (unsigned short*)(ws + 65536);
    unsigned short* Wbl  = Wbh + WB_N;
    unsigned short* nlwh = Wbl + WB_N;
    unsigned short* nlwl = nlwh + NLW_N;
    unsigned short* nlWh = nlwl + NLW_N;
    unsigned short* nlWl = nlWh + NLWW_N;  // ends at float 491520
    float* Z = ws + 491520;
    float* T = Z + ELEMS;

    // fused head: prep_w + adj + prep_vt + stats-zero in ONE dispatch
    prep_all_kernel<<<PREPW_BLKS + 15 + 14, 256, 0, stream>>>(
        W_res, nl_g_w, nl_t_w, nl_p_w, nl_W_w,
        Wbh, Wbl, nlwh, nlwl, nlWh, nlWl,
        gc_in_e, e_res, gc_out_e, mask_rows, mask_cols, nnz,
        off_all, diag_all,
        nl_t_b, nl_cp_w, vt, ct, stats);

    // t0 -> T, slot 0
    gconv_in_kernel<<<B, 256, 0, stream>>>(x, gc_in_W, gc_in_b, off_all, diag_all,
                                           T, stats);
    // nonlocal 0: h0 -> Z; wy -> T, slot 1
    nl_a_kernel<<<B, 512, 0, stream>>>(T, stats, bn_in_g, bn_in_b, nullptr,
                                       nlwh, nlwl, nl_g_b, nl_p_b, nl_cp_w,
                                       vt, ct, nlWh, nlWl, nl_W_b, restored,
                                       Z, T, stats + SLOT);

    int sl = 1;
    for (int i = 0; i < NLAYERS; i++) {
        int l0 = 2 * i, l1 = 2 * i + 1, li = i + 1;
        // gconv1 + fused nl_b: z -> Z; t1 -> T, slot sl+1
        gconv_mfma_kernel<<<2048, 256, 0, stream>>>(
            Z, T, stats + (size_t)sl * SLOT,
            nl_bn_g + i * 128, nl_bn_b + i * 128, restored, Z,
            Wbh + (size_t)l0 * 32768, Wbl + (size_t)l0 * 32768, b_res + l0 * 128,
            off_all + (1 + l0) * 256, diag_all + (1 + l0) * 16, T,
            stats + (size_t)(sl + 1) * SLOT);
        // gconv2: t2 -> T, slot sl+2
        gconv_mfma_kernel<<<2048, 256, 0, stream>>>(
            T, nullptr, stats + (size_t)(sl + 1) * SLOT,
            bng_res + l0 * 128, bnb_res + l0 * 128, nullptr, nullptr,
            Wbh + (size_t)l1 * 32768, Wbl + (size_t)l1 * 32768, b_res + l1 * 128,
            off_all + (1 + l1) * 256, diag_all + (1 + l1) * 16, T,
            stats + (size_t)(sl + 2) * SLOT);
        // nl_a: h -> Z; wy -> T, slot sl+3
        nl_a_kernel<<<B, 512, 0, stream>>>(
            T, stats + (size_t)(sl + 2) * SLOT,
            bng_res + l1 * 128, bnb_res + l1 * 128, Z,
            nlwh + li * 24576, nlwl + li * 24576,
            nl_g_b + li * 64, nl_p_b + li * 64, nl_cp_w + li * 128,
            vt + li * 128, ct + li, nlWh + li * 8192, nlWl + li * 8192,
            nl_W_b + li * 128, restored, Z, T,
            stats + (size_t)(sl + 3) * SLOT);
        sl += 3;
    }
    gconv_out_kernel<<<B, 256, 0, stream>>>(Z, T, stats + (size_t)sl * SLOT,
                                            nl_bn_g + NLAYERS * 128, nl_bn_b + NLAYERS * 128,
                                            restored, gc_out_W, gc_out_b,
                                            off_all + 9 * 256, diag_all + 9 * 16,
                                            (float*)d_out);
}